// Round 7
// baseline (233.127 us; speedup 1.0000x reference)
//
#include <hip/hip_runtime.h>
#include <hip/hip_bf16.h>
#include <cstdint>
#include <cstddef>
#include <math.h>

#define HEADS 8
#define DHEAD 64
#define INNER 512
#define BATCH 2
#define SEQ   2048
#define MROWS (BATCH*SEQ)   /* 4096 */
#define LN_EPS 1e-6f
#define KSPLIT 4
#define KCHUNK (SEQ/KSPLIT) /* 512 */

typedef unsigned short u16;
typedef __attribute__((ext_vector_type(8))) short short8;
typedef __attribute__((ext_vector_type(4))) short short4v;
typedef __attribute__((ext_vector_type(4))) float f32x4;

#define MFMA16(a,b,c) __builtin_amdgcn_mfma_f32_16x16x32_bf16((a),(b),(c),0,0,0)
#if __has_builtin(__builtin_amdgcn_mfma_f32_16x16x16bf16_1k)
#define HAVE_MFMA16K16 1
#define MFMA16K16(a,b,c) __builtin_amdgcn_mfma_f32_16x16x16bf16_1k((a),(b),(c),0,0,0)
#endif

__device__ __forceinline__ float bf2f(u16 u) {
    union { float f; uint32_t i; } x; x.i = ((uint32_t)u) << 16; return x.f;
}
__device__ __forceinline__ u16 f2bf(float f) {
    __hip_bfloat16 h = __float2bfloat16(f);   // RNE
    return *reinterpret_cast<u16*>(&h);
}
__device__ __forceinline__ void gl_lds16(const void* g, void* l) {
    __builtin_amdgcn_global_load_lds(
        (const __attribute__((address_space(1))) void*)g,
        (__attribute__((address_space(3))) void*)l, 16, 0, 0);
}

// ---------------------------------------------------------------- prep
// Fused: x fp32->bf16 (blocks 0..2047) + 4 weight transposes to [N][K] bf16.
__global__ void prep_kernel(const float* __restrict__ x, u16* __restrict__ x_b,
                            const float* __restrict__ w_qkv, u16* __restrict__ w_qkvT,
                            const float* __restrict__ w_out, u16* __restrict__ w_outT,
                            const float* __restrict__ w_ff1, u16* __restrict__ w_ff1T,
                            const float* __restrict__ w_ff2, u16* __restrict__ w_ff2T) {
    __shared__ float T[32][33];
    const int blk = blockIdx.x, tid = threadIdx.x;
    if (blk < 2048) {
        int i = blk * 256 + tid;
        float4 v = reinterpret_cast<const float4*>(x)[i];
        ushort4 o;
        o.x = f2bf(v.x); o.y = f2bf(v.y); o.z = f2bf(v.z); o.w = f2bf(v.w);
        reinterpret_cast<ushort4*>(x_b)[i] = o;
        return;
    }
    const float* B; u16* Bt; int K, N, t;
    if (blk < 2816)      { B = w_qkv; Bt = w_qkvT; K = 512;  N = 1536; t = blk - 2048; }
    else if (blk < 3072) { B = w_out; Bt = w_outT; K = 512;  N = 512;  t = blk - 2816; }
    else if (blk < 4096) { B = w_ff1; Bt = w_ff1T; K = 512;  N = 2048; t = blk - 3072; }
    else                 { B = w_ff2; Bt = w_ff2T; K = 2048; N = 512;  t = blk - 4096; }
    const int nb = N / 32;
    const int n0 = (t % nb) * 32, k0 = (t / nb) * 32;
    const int r = tid >> 3, c = (tid & 7) * 4;
    float4 v = *reinterpret_cast<const float4*>(&B[(size_t)(k0 + r) * N + n0 + c]);
    T[c + 0][r] = v.x; T[c + 1][r] = v.y; T[c + 2][r] = v.z; T[c + 3][r] = v.w;
    __syncthreads();
    ushort4 o;
    o.x = f2bf(T[r][c + 0]); o.y = f2bf(T[r][c + 1]);
    o.z = f2bf(T[r][c + 2]); o.w = f2bf(T[r][c + 3]);
    *reinterpret_cast<ushort4*>(&Bt[(size_t)(n0 + r) * K + k0 + c]) = o;
}

// ---------------------------------------------------------------- MFMA GEMM
// C[M,N] = A[M,K](bf16) @ Bt[N,K](bf16)^T. 128xBN tile, BK=32, 4 waves.
// EPI: 0 = bf16 out; 2 = QKV routing; 3 = bf16 split-K partial.
template<int BN, int EPI>
__global__ __launch_bounds__(256) void gemm_bt(const u16* __restrict__ A,
                                               const u16* __restrict__ Bt,
                                               u16* __restrict__ Cb,
                                               u16* __restrict__ Vt,
                                               int M, int N, int K) {
    constexpr int WN = BN / 2;
    constexpr int NT = WN / 16;
    __shared__ u16 As[128 * 32];
    __shared__ u16 Bs[BN * 32];
    const int tid = threadIdx.x;
    const int wave = tid >> 6, lane = tid & 63;
    const int l15 = lane & 15, quad = lane >> 4;
    const int wm = (wave >> 1) * 64, wn = (wave & 1) * WN;
    const int row0 = blockIdx.y * 128, col0 = blockIdx.x * BN;

    int kbase = 0, kend = K;
    if (EPI == 3) {
        int chunk = K / gridDim.z;
        kbase = blockIdx.z * chunk; kend = kbase + chunk;
    }

    f32x4 acc[4][NT];
    #pragma unroll
    for (int mi = 0; mi < 4; ++mi)
        #pragma unroll
        for (int ni = 0; ni < NT; ++ni)
            #pragma unroll
            for (int e = 0; e < 4; ++e) acc[mi][ni][e] = 0.f;

    for (int k0 = kbase; k0 < kend; k0 += 32) {
        #pragma unroll
        for (int idx0 = 0; idx0 < 512 + BN * 4; idx0 += 256) {
            int idx = idx0 + tid;
            if (idx < 512) {
                int r = idx >> 2, ic = (idx & 3) * 8;
                gl_lds16(A + (size_t)(row0 + r) * K + k0 + ic, &As[idx * 8]);
            } else {
                int ib = idx - 512;
                int r = ib >> 2, ic = (ib & 3) * 8;
                gl_lds16(Bt + (size_t)(col0 + r) * K + k0 + ic, &Bs[ib * 8]);
            }
        }
        __syncthreads();

        short8 af[4], bfr[NT];
        #pragma unroll
        for (int mi = 0; mi < 4; ++mi)
            af[mi] = *reinterpret_cast<const short8*>(&As[(wm + mi * 16 + l15) * 32 + quad * 8]);
        #pragma unroll
        for (int ni = 0; ni < NT; ++ni)
            bfr[ni] = *reinterpret_cast<const short8*>(&Bs[(wn + ni * 16 + l15) * 32 + quad * 8]);
        #pragma unroll
        for (int mi = 0; mi < 4; ++mi)
            #pragma unroll
            for (int ni = 0; ni < NT; ++ni)
                acc[mi][ni] = MFMA16(af[mi], bfr[ni], acc[mi][ni]);
        __syncthreads();
    }

    #pragma unroll
    for (int mi = 0; mi < 4; ++mi)
        #pragma unroll
        for (int ni = 0; ni < NT; ++ni) {
            const int cc = col0 + wn + ni * 16 + l15;
            const int rr0 = row0 + wm + mi * 16 + quad * 4;
            if (EPI == 0) {
                #pragma unroll
                for (int r = 0; r < 4; ++r)
                    Cb[(size_t)(rr0 + r) * N + cc] = f2bf(acc[mi][ni][r]);
            } else if (EPI == 3) {
                u16* Cz = Cb + (size_t)blockIdx.z * M * N;
                #pragma unroll
                for (int r = 0; r < 4; ++r)
                    Cz[(size_t)(rr0 + r) * N + cc] = f2bf(acc[mi][ni][r]);
            } else {  // EPI == 2: QKV routing
                if (cc < 1024) {
                    size_t base = (cc < 512) ? (size_t)cc
                                             : ((size_t)MROWS * 512 + cc - 512);
                    #pragma unroll
                    for (int r = 0; r < 4; ++r)
                        Cb[base + (size_t)(rr0 + r) * 512] = f2bf(acc[mi][ni][r]);
                } else {
                    int hh = (cc - 1024) >> 6, dd = (cc - 1024) & 63;
                    int bb = rr0 >> 11, srow = rr0 & 2047;
                    ushort4 o;
                    o.x = f2bf(acc[mi][ni][0]); o.y = f2bf(acc[mi][ni][1]);
                    o.z = f2bf(acc[mi][ni][2]); o.w = f2bf(acc[mi][ni][3]);
                    *reinterpret_cast<ushort4*>(
                        &Vt[(((size_t)(bb * 8 + hh) * 64 + dd) << 11) + srow]) = o;
                }
            }
        }
}

// ---------------------------------------------------------------- proj GEMM
// proj[M,512] = combine(Opart,l) @ w_outT^T + b_out. 64x64 tile, 4 waves
// (2x2), BK=32. A-tile is produced during staging: A = (sum_ks O)/(sum_ks l).
__global__ __launch_bounds__(256) void gemm_proj(const u16* __restrict__ OpartB,
                                                 const float* __restrict__ lpart,
                                                 const u16* __restrict__ Bt,
                                                 const float* __restrict__ bias,
                                                 float* __restrict__ C) {
    __shared__ u16 As[64 * 32];
    __shared__ u16 Bs[64 * 32];
    const int tid = threadIdx.x;
    const int wave = tid >> 6, lane = tid & 63;
    const int l15 = lane & 15, quad = lane >> 4;
    const int wm = (wave >> 1) * 32, wn = (wave & 1) * 32;
    const int row0 = blockIdx.y * 64, col0 = blockIdx.x * 64;

    f32x4 acc[2][2];
    #pragma unroll
    for (int mi = 0; mi < 2; ++mi)
        #pragma unroll
        for (int ni = 0; ni < 2; ++ni)
            #pragma unroll
            for (int e = 0; e < 4; ++e) acc[mi][ni][e] = 0.f;

    const int r = tid >> 2, ic = (tid & 3) * 8;   // staging chunk (1 per thread)
    const int gr = row0 + r;
    const int bb = gr >> 11, srow = gr & 2047;

    for (int k0 = 0; k0 < 512; k0 += 32) {
        // B via DMA
        gl_lds16(Bt + (size_t)(col0 + r) * 512 + k0 + ic, &Bs[tid * 8]);
        // A = combined attention output, computed in-registers
        {
            const int gc = k0 + ic;
            const int h = gc >> 6, d0 = gc & 63;
            const int bh = bb * 8 + h;
            float l = 0.f, o[8] = {0.f, 0.f, 0.f, 0.f, 0.f, 0.f, 0.f, 0.f};
            #pragma unroll
            for (int ks = 0; ks < KSPLIT; ++ks) {
                size_t pk = ((size_t)(ks * 16 + bh) << 11) + srow;
                l += lpart[pk];
                uint4 uv = *reinterpret_cast<const uint4*>(&OpartB[pk * 64 + d0]);
                const u16* up = (const u16*)&uv;
                #pragma unroll
                for (int i = 0; i < 8; ++i) o[i] += bf2f(up[i]);
            }
            float inv = 1.f / l;
            u16 a8[8];
            #pragma unroll
            for (int i = 0; i < 8; ++i) a8[i] = f2bf(o[i] * inv);
            *reinterpret_cast<uint4*>(&As[tid * 8]) =
                *reinterpret_cast<const uint4*>(a8);
        }
        __syncthreads();

        short8 af[2], bfr[2];
        #pragma unroll
        for (int mi = 0; mi < 2; ++mi)
            af[mi] = *reinterpret_cast<const short8*>(&As[(wm + mi * 16 + l15) * 32 + quad * 8]);
        #pragma unroll
        for (int ni = 0; ni < 2; ++ni)
            bfr[ni] = *reinterpret_cast<const short8*>(&Bs[(wn + ni * 16 + l15) * 32 + quad * 8]);
        #pragma unroll
        for (int mi = 0; mi < 2; ++mi)
            #pragma unroll
            for (int ni = 0; ni < 2; ++ni)
                acc[mi][ni] = MFMA16(af[mi], bfr[ni], acc[mi][ni]);
        __syncthreads();
    }

    #pragma unroll
    for (int mi = 0; mi < 2; ++mi)
        #pragma unroll
        for (int ni = 0; ni < 2; ++ni) {
            const int cc = col0 + wn + ni * 16 + l15;
            const int rr0 = row0 + wm + mi * 16 + quad * 4;
            #pragma unroll
            for (int rr = 0; rr < 4; ++rr)
                C[(size_t)(rr0 + rr) * 512 + cc] = acc[mi][ni][rr] + bias[cc];
        }
}

// ---------------------------------------------------------------- attention
// Block = (qtile 64, bh, ksplit 4). S^T = K*Q^T; exp'd P feeds PV directly
// from registers via mfma 16x16x16. O^T transposed via LDS in epilogue.
__global__ __launch_bounds__(256) void attn_kernel(const u16* __restrict__ qk_b,
                                                   const u16* __restrict__ vT_b,
                                                   u16* __restrict__ OpartB,
                                                   float* __restrict__ lpart) {
    __shared__ u16 SM[64 * 64 + 2 * 64 * 72];
    u16 (*Qs)[64] = (u16(*)[64])SM;
    u16 (*Ks)[72] = (u16(*)[72])(SM + 64 * 64);
    u16 (*VT)[72] = (u16(*)[72])(SM + 64 * 64 + 64 * 72);

    const int tid = threadIdx.x;
    const int wave = tid >> 6, lane = tid & 63;
    const int l15 = lane & 15, quad = lane >> 4;
    const int qt = blockIdx.x, bh = blockIdx.y, ks = blockIdx.z;
    const int b = bh >> 3, h = bh & 7;
    const int w16 = wave * 16;
    const int r0 = tid >> 3, r1 = r0 + 32;
    const int ch = (tid & 7) * 8;

    // stage Q [64][64]
    {
        const u16* qb = qk_b + (size_t)(b * SEQ + qt * 64) * 512 + h * 64;
        *reinterpret_cast<uint4*>(&Qs[r0][ch]) =
            *reinterpret_cast<const uint4*>(&qb[(size_t)r0 * 512 + ch]);
        *reinterpret_cast<uint4*>(&Qs[r1][ch]) =
            *reinterpret_cast<const uint4*>(&qb[(size_t)r1 * 512 + ch]);
    }
    __syncthreads();

    short8 qf[2];
    qf[0] = *reinterpret_cast<const short8*>(&Qs[w16 + l15][quad * 8]);
    qf[1] = *reinterpret_cast<const short8*>(&Qs[w16 + l15][32 + quad * 8]);

    const u16* kb = qk_b + (size_t)MROWS * 512
                  + (size_t)(b * SEQ + ks * KCHUNK) * 512 + h * 64;
    const u16* vb = vT_b + (size_t)bh * 64 * 2048 + ks * KCHUNK;

    uint4 kr0 = *reinterpret_cast<const uint4*>(&kb[(size_t)r0 * 512 + ch]);
    uint4 kr1 = *reinterpret_cast<const uint4*>(&kb[(size_t)r1 * 512 + ch]);
    uint4 vr0 = *reinterpret_cast<const uint4*>(&vb[(size_t)r0 * 2048 + ch]);
    uint4 vr1 = *reinterpret_cast<const uint4*>(&vb[(size_t)r1 * 2048 + ch]);

    const float CEXP = 0.18033688011110918f;   // 0.125 * log2(e)

#ifdef HAVE_MFMA16K16
    f32x4 oacc[4];
    float lsum = 0.f;
    #pragma unroll
    for (int di = 0; di < 4; ++di)
        #pragma unroll
        for (int e = 0; e < 4; ++e) oacc[di][e] = 0.f;

    for (int kt = 0; kt < KCHUNK / 64; ++kt) {
        *reinterpret_cast<uint4*>(&Ks[r0][ch]) = kr0;
        *reinterpret_cast<uint4*>(&Ks[r1][ch]) = kr1;
        *reinterpret_cast<uint4*>(&VT[r0][ch]) = vr0;
        *reinterpret_cast<uint4*>(&VT[r1][ch]) = vr1;
        __syncthreads();

        if (kt + 1 < KCHUNK / 64) {
            const u16* kb2 = kb + (size_t)(kt + 1) * 64 * 512;
            const u16* vb2 = vb + (kt + 1) * 64;
            kr0 = *reinterpret_cast<const uint4*>(&kb2[(size_t)r0 * 512 + ch]);
            kr1 = *reinterpret_cast<const uint4*>(&kb2[(size_t)r1 * 512 + ch]);
            vr0 = *reinterpret_cast<const uint4*>(&vb2[(size_t)r0 * 2048 + ch]);
            vr1 = *reinterpret_cast<const uint4*>(&vb2[(size_t)r1 * 2048 + ch]);
        }

        f32x4 sacc[4];
        #pragma unroll
        for (int ni = 0; ni < 4; ++ni)
            #pragma unroll
            for (int e = 0; e < 4; ++e) sacc[ni][e] = 0.f;
        #pragma unroll
        for (int ksk = 0; ksk < 2; ++ksk) {
            short8 kf[4];
            #pragma unroll
            for (int ni = 0; ni < 4; ++ni)
                kf[ni] = *reinterpret_cast<const short8*>(
                    &Ks[ni * 16 + l15][ksk * 32 + quad * 8]);
            #pragma unroll
            for (int ni = 0; ni < 4; ++ni)
                sacc[ni] = MFMA16(kf[ni], qf[ksk], sacc[ni]);   // A=K, B=Q^T
        }

        #pragma unroll
        for (int ni = 0; ni < 4; ++ni) {
            short4v pp;
            #pragma unroll
            for (int r = 0; r < 4; ++r) {
                float p = exp2f(sacc[ni][r] * CEXP);
                lsum += p;
                pp[r] = (short)f2bf(p);
            }
            #pragma unroll
            for (int di = 0; di < 4; ++di) {
                short4v vf = *reinterpret_cast<const short4v*>(
                    &VT[di * 16 + l15][ni * 16 + quad * 4]);
                oacc[di] = MFMA16K16(vf, pp, oacc[di]);   // O^T += V^T P^T
            }
        }
        __syncthreads();
    }

    lsum += __shfl_xor(lsum, 16);
    lsum += __shfl_xor(lsum, 32);

    const size_t pbase = ((size_t)(ks * 16 + bh) * SEQ + qt * 64);
    if (lane < 16) lpart[pbase + w16 + lane] = lsum;

    // transpose O^T -> row-major bf16 partial via LDS
    float* OTf = (float*)SM;   // [64 d][68 q]
    #pragma unroll
    for (int di = 0; di < 4; ++di)
        #pragma unroll
        for (int r = 0; r < 4; ++r)
            OTf[(di * 16 + quad * 4 + r) * 68 + w16 + l15] = oacc[di][r];
    __syncthreads();

    const int ql = tid >> 2, dseg = (tid & 3) * 16;
    u16 ov[16];
    #pragma unroll
    for (int i = 0; i < 16; ++i) ov[i] = f2bf(OTf[(dseg + i) * 68 + ql]);
    u16* op = &OpartB[(pbase + ql) * 64 + dseg];
    *reinterpret_cast<uint4*>(op)     = *reinterpret_cast<const uint4*>(ov);
    *reinterpret_cast<uint4*>(op + 8) = *reinterpret_cast<const uint4*>(ov + 8);
#else
    // fallback: P via LDS round-trip through Qs
    f32x4 oacc[4];
    float lsum[4];
    #pragma unroll
    for (int di = 0; di < 4; ++di)
        #pragma unroll
        for (int e = 0; e < 4; ++e) oacc[di][e] = 0.f;
    #pragma unroll
    for (int r = 0; r < 4; ++r) lsum[r] = 0.f;

    for (int kt = 0; kt < KCHUNK / 64; ++kt) {
        *reinterpret_cast<uint4*>(&Ks[r0][ch]) = kr0;
        *reinterpret_cast<uint4*>(&Ks[r1][ch]) = kr1;
        *reinterpret_cast<uint4*>(&VT[r0][ch]) = vr0;
        *reinterpret_cast<uint4*>(&VT[r1][ch]) = vr1;
        __syncthreads();

        if (kt + 1 < KCHUNK / 64) {
            const u16* kb2 = kb + (size_t)(kt + 1) * 64 * 512;
            const u16* vb2 = vb + (kt + 1) * 64;
            kr0 = *reinterpret_cast<const uint4*>(&kb2[(size_t)r0 * 512 + ch]);
            kr1 = *reinterpret_cast<const uint4*>(&kb2[(size_t)r1 * 512 + ch]);
            vr0 = *reinterpret_cast<const uint4*>(&vb2[(size_t)r0 * 2048 + ch]);
            vr1 = *reinterpret_cast<const uint4*>(&vb2[(size_t)r1 * 2048 + ch]);
        }

        f32x4 sacc[4];
        #pragma unroll
        for (int ni = 0; ni < 4; ++ni)
            #pragma unroll
            for (int e = 0; e < 4; ++e) sacc[ni][e] = 0.f;
        #pragma unroll
        for (int ksk = 0; ksk < 2; ++ksk) {
            short8 kf[4];
            #pragma unroll
            for (int ni = 0; ni < 4; ++ni)
                kf[ni] = *reinterpret_cast<const short8*>(
                    &Ks[ni * 16 + l15][ksk * 32 + quad * 8]);
            #pragma unroll
            for (int ni = 0; ni < 4; ++ni)
                sacc[ni] = MFMA16(qf[ksk], kf[ni], sacc[ni]);
        }
        #pragma unroll
        for (int ni = 0; ni < 4; ++ni)
            #pragma unroll
            for (int r = 0; r < 4; ++r) {
                float p = exp2f(sacc[ni][r] * CEXP);
                lsum[r] += p;
                Qs[w16 + quad * 4 + r][ni * 16 + l15] = f2bf(p);
            }
        #pragma unroll
        for (int ksk = 0; ksk < 2; ++ksk) {
            short8 pf = *reinterpret_cast<const short8*>(
                &Qs[w16 + l15][ksk * 32 + quad * 8]);
            #pragma unroll
            for (int di = 0; di < 4; ++di) {
                short8 vf = *reinterpret_cast<const short8*>(
                    &VT[di * 16 + l15][ksk * 32 + quad * 8]);
                oacc[di] = MFMA16(pf, vf, oacc[di]);
            }
        }
        __syncthreads();
    }

    #pragma unroll
    for (int r = 0; r < 4; ++r) {
        float v = lsum[r];
        v += __shfl_xor(v, 1); v += __shfl_xor(v, 2);
        v += __shfl_xor(v, 4); v += __shfl_xor(v, 8);
        lsum[r] = v;
    }
    const size_t pbase = ((size_t)(ks * 16 + bh) * SEQ + qt * 64);
    #pragma unroll
    for (int di = 0; di < 4; ++di)
        #pragma unroll
        for (int r = 0; r < 4; ++r)
            OpartB[(pbase + w16 + quad * 4 + r) * 64 + di * 16 + l15] = f2bf(oacc[di][r]);
    if (l15 == 0)
        #pragma unroll
        for (int r = 0; r < 4; ++r)
            lpart[pbase + w16 + quad * 4 + r] = lsum[r];
#endif
}

// ---------------------------------------------------------------- layernorm
// One wave per row (512 cols = 8/lane), shuffle-only reduction, no barriers.
template<bool A16, bool S16, bool TWO>
__global__ __launch_bounds__(256) void ln_kernel(const void* __restrict__ a_,
                                                 const void* __restrict__ s0_,
                                                 const void* __restrict__ s1_,
                                                 const float* __restrict__ g,
                                                 const float* __restrict__ be,
                                                 float* __restrict__ out32,
                                                 u16* __restrict__ out16) {
    const int tid = threadIdx.x, wave = tid >> 6, lane = tid & 63;
    const int row = blockIdx.x * 4 + wave;
    const size_t off = (size_t)row * INNER;

    float v[8];
    #pragma unroll
    for (int j = 0; j < 2; ++j) {
        const int c = j * 256 + lane * 4;
        float a0, a1, a2, a3;
        if (A16) {
            ushort4 u = *reinterpret_cast<const ushort4*>((const u16*)a_ + off + c);
            a0 = bf2f(u.x); a1 = bf2f(u.y); a2 = bf2f(u.z); a3 = bf2f(u.w);
        } else {
            float4 u = *reinterpret_cast<const float4*>((const float*)a_ + off + c);
            a0 = u.x; a1 = u.y; a2 = u.z; a3 = u.w;
        }
        float s0, s1, s2, s3;
        if (S16) {
            ushort4 u = *reinterpret_cast<const ushort4*>((const u16*)s0_ + off + c);
            s0 = bf2f(u.x); s1 = bf2f(u.y); s2 = bf2f(u.z); s3 = bf2f(u.w);
        } else {
            float4 u = *reinterpret_cast<const float4*>((const float*)s0_ + off + c);
            s0 = u.x; s1 = u.y; s2 = u.z; s3 = u.w;
        }
        v[j*4+0] = a0 + s0; v[j*4+1] = a1 + s1; v[j*4+2] = a2 + s2; v[j*4+3] = a3 + s3;
        if (TWO) {
            if (S16) {
                ushort4 u = *reinterpret_cast<const ushort4*>((const u16*)s1_ + off + c);
                v[j*4+0] += bf2f(u.x); v[j*4+1] += bf2f(u.y);
                v[j*4+2] += bf2f(u.z); v[j*4+3] += bf2f(u.w);
            } else {
                float4 u = *reinterpret_cast<const float4*>((const float*)s1_ + off + c);
                v[j*4+0] += u.x; v[j*4+1] += u.y; v[j*4+2] += u.z; v[j*4+3] += u.w;
            }
        }
    }

    float s = 0.f;
    #pragma unroll
    for (int i = 0; i < 8; ++i) s += v[i];
    #pragma unroll
    for (int m = 1; m < 64; m <<= 1) s += __shfl_xor(s, m);
    const float mu = s * (1.f / INNER);

    float q = 0.f;
    #pragma unroll
    for (int i = 0; i < 8; ++i) { v[i] -= mu; q += v[i] * v[i]; }
    #pragma unroll
    for (int m = 1; m < 64; m <<= 1) q += __shfl_xor(q, m);
    const float rstd = rsqrtf(q * (1.f / INNER) + LN_EPS);

    #pragma unroll
    for (int j = 0; j < 2; ++j) {
        const int c = j * 256 + lane * 4;
        float4 gv = *reinterpret_cast<const float4*>(g + c);
        float4 bv = *reinterpret_cast<const float4*>(be + c);
        float y0 = v[j*4+0] * rstd * gv.x + bv.x;
        float y1 = v[j*4+1] * rstd * gv.y + bv.y;
        float y2 = v[j*4+2] * rstd * gv.z + bv.z;
        float y3 = v[j*4+3] * rstd * gv.w + bv.w;
        if (out32) {
            float4 o = {y0, y1, y2, y3};
            *reinterpret_cast<float4*>(out32 + off + c) = o;
        }
        if (out16) {
            ushort4 o;
            o.x = f2bf(y0); o.y = f2bf(y1); o.z = f2bf(y2); o.w = f2bf(y3);
            *reinterpret_cast<ushort4*>(out16 + off + c) = o;
        }
    }
}

// ---------------------------------------------------------------- launch
extern "C" void kernel_launch(void* const* d_in, const int* in_sizes, int n_in,
                              void* d_out, int out_size, void* d_ws, size_t ws_size,
                              hipStream_t stream) {
    const float* x     = (const float*)d_in[0];
    const float* w_qkv = (const float*)d_in[1];
    const float* w_out = (const float*)d_in[2];
    const float* b_out = (const float*)d_in[3];
    const float* w_ff1 = (const float*)d_in[4];
    const float* w_ff2 = (const float*)d_in[5];
    const float* g1    = (const float*)d_in[6];
    const float* be1   = (const float*)d_in[7];
    const float* g2    = (const float*)d_in[8];
    const float* be2   = (const float*)d_in[9];
    float* out = (float*)d_out;

    char* W = (char*)d_ws;
    // Phases: A prep, B qkv, C attn, E proj(+combine), F LN1, G ff1, H ff2, I LN2
    u16*   w_outT     = (u16*)  (W + 0);          // 0.52 [A->E]
    u16*   w_ff1T     = (u16*)  (W + 524288);     // 2.10 [A->G]
    u16*   w_ff2T     = (u16*)  (W + 2621440);    // 2.10 [A->H]
    u16*   qk_b       = (u16*)  (W + 4718592);    // 8.39 (q then k) [B->C]
    float* proj       = (float*)(W + 4718592);    // 8.39 [E->F] (reuse qk_b)
    u16*   ff2p       = (u16*)  (W + 4718592);    // 8.39 (2 bf16 partials) [H->I] (reuse proj)
    u16*   vT_b       = (u16*)  (W + 13107200);   // 4.19 [B->C]
    u16*   attn_res_b = (u16*)  (W + 13107200);   // 4.19 [F->I] (reuse vT_b)
    u16*   x_b        = (u16*)  (W + 17301504);   // 4.19 [A->B]
    u16*   w_qkvT     = (u16*)  (W + 21495808);   // 1.57 [A->B]
    u16*   OpartB     = (u16*)  (W + 17301504);   // 16.78 [C->E] (reuse x_b+w_qkvT)
    u16*   ff1_b      = (u16*)  (W + 17301504);   // 16.78 [G->H] (reuse OpartB)
    float* lpart      = (float*)(W + 34078720);   // 0.52 [C->E]  ends 34603008

    // A) fused prep: x->bf16 + 4 weight transposes (5120 blocks)
    prep_kernel<<<5120, 256, 0, stream>>>(x, x_b, w_qkv, w_qkvT, w_out, w_outT,
                                          w_ff1, w_ff1T, w_ff2, w_ff2T);

    // B) qkv = x @ w_qkv -> q/k rowmajor, V transposed (BN=64: 768 blocks, 3/CU)
    gemm_bt<64, 2><<<dim3(1536 / 64, MROWS / 128), 256, 0, stream>>>(
        x_b, w_qkvT, qk_b, vT_b, MROWS, 1536, INNER);

    // C) attention partials (2048 blocks, 6 blocks/CU resident)
    attn_kernel<<<dim3(SEQ / 64, BATCH * HEADS, KSPLIT), 256, 0, stream>>>(
        qk_b, vT_b, OpartB, lpart);

    // E) proj = combine(Opart) @ w_out + b_out -> fp32  (512 blocks, 2/CU)
    gemm_proj<<<dim3(INNER / 64, MROWS / 64), 256, 0, stream>>>(
        OpartB, lpart, w_outT, b_out, proj);

    // F) attn_res = LN(x + proj) -> bf16
    ln_kernel<false, false, false><<<MROWS / 4, 256, 0, stream>>>(
        x, proj, nullptr, g1, be1, nullptr, attn_res_b);

    // G) ff1 = attn_res @ w_ff1 -> bf16  (512 blocks)
    gemm_bt<128, 0><<<dim3(2048 / 128, MROWS / 128), 256, 0, stream>>>(
        attn_res_b, w_ff1T, ff1_b, nullptr, MROWS, 2048, INNER);

    // H) ff2 partials = ff1 @ w_ff2 (split-K=2) -> bf16 x2  (512 blocks)
    gemm_bt<64, 3><<<dim3(INNER / 64, MROWS / 128, 2), 256, 0, stream>>>(
        ff1_b, w_ff2T, ff2p, nullptr, MROWS, INNER, 2048);

    // I) out = LN(attn_res + ff2p0 + ff2p1) -> fp32 d_out
    ln_kernel<true, true, true><<<MROWS / 4, 256, 0, stream>>>(
        attn_res_b, ff2p, ff2p + (size_t)MROWS * INNER, g2, be2, out, nullptr);
}

// Round 8
// 210.987 us; speedup vs baseline: 1.1049x; 1.1049x over previous
//
#include <hip/hip_runtime.h>
#include <hip/hip_bf16.h>
#include <cstdint>
#include <cstddef>
#include <math.h>

#define HEADS 8
#define DHEAD 64
#define INNER 512
#define BATCH 2
#define SEQ   2048
#define MROWS (BATCH*SEQ)   /* 4096 */
#define LN_EPS 1e-6f
#define KSPLIT 4
#define KCHUNK (SEQ/KSPLIT) /* 512 */
#define QSCALE 0.18033688011110918f   /* 0.125 * log2(e), folded into Q */

typedef unsigned short u16;
typedef __attribute__((ext_vector_type(8))) short short8;
typedef __attribute__((ext_vector_type(4))) short short4v;
typedef __attribute__((ext_vector_type(4))) float f32x4;

#define MFMA16(a,b,c) __builtin_amdgcn_mfma_f32_16x16x32_bf16((a),(b),(c),0,0,0)
#if __has_builtin(__builtin_amdgcn_mfma_f32_16x16x16bf16_1k)
#define HAVE_MFMA16K16 1
#define MFMA16K16(a,b,c) __builtin_amdgcn_mfma_f32_16x16x16bf16_1k((a),(b),(c),0,0,0)
#endif

__device__ __forceinline__ float bf2f(u16 u) {
    union { float f; uint32_t i; } x; x.i = ((uint32_t)u) << 16; return x.f;
}
__device__ __forceinline__ u16 f2bf(float f) {
    __hip_bfloat16 h = __float2bfloat16(f);   // RNE
    return *reinterpret_cast<u16*>(&h);
}
__device__ __forceinline__ void gl_lds16(const void* g, void* l) {
    __builtin_amdgcn_global_load_lds(
        (const __attribute__((address_space(1))) void*)g,
        (__attribute__((address_space(3))) void*)l, 16, 0, 0);
}

// ---------------------------------------------------------------- prep
// Fused: x fp32->bf16 (blocks 0..2047) + 4 weight transposes to [N][K] bf16.
__global__ void prep_kernel(const float* __restrict__ x, u16* __restrict__ x_b,
                            const float* __restrict__ w_qkv, u16* __restrict__ w_qkvT,
                            const float* __restrict__ w_out, u16* __restrict__ w_outT,
                            const float* __restrict__ w_ff1, u16* __restrict__ w_ff1T,
                            const float* __restrict__ w_ff2, u16* __restrict__ w_ff2T) {
    __shared__ float T[32][33];
    const int blk = blockIdx.x, tid = threadIdx.x;
    if (blk < 2048) {
        int i = blk * 256 + tid;
        float4 v = reinterpret_cast<const float4*>(x)[i];
        ushort4 o;
        o.x = f2bf(v.x); o.y = f2bf(v.y); o.z = f2bf(v.z); o.w = f2bf(v.w);
        reinterpret_cast<ushort4*>(x_b)[i] = o;
        return;
    }
    const float* B; u16* Bt; int K, N, t;
    if (blk < 2816)      { B = w_qkv; Bt = w_qkvT; K = 512;  N = 1536; t = blk - 2048; }
    else if (blk < 3072) { B = w_out; Bt = w_outT; K = 512;  N = 512;  t = blk - 2816; }
    else if (blk < 4096) { B = w_ff1; Bt = w_ff1T; K = 512;  N = 2048; t = blk - 3072; }
    else                 { B = w_ff2; Bt = w_ff2T; K = 2048; N = 512;  t = blk - 4096; }
    const int nb = N / 32;
    const int n0 = (t % nb) * 32, k0 = (t / nb) * 32;
    const int r = tid >> 3, c = (tid & 7) * 4;
    float4 v = *reinterpret_cast<const float4*>(&B[(size_t)(k0 + r) * N + n0 + c]);
    T[c + 0][r] = v.x; T[c + 1][r] = v.y; T[c + 2][r] = v.z; T[c + 3][r] = v.w;
    __syncthreads();
    ushort4 o;
    o.x = f2bf(T[r][c + 0]); o.y = f2bf(T[r][c + 1]);
    o.z = f2bf(T[r][c + 2]); o.w = f2bf(T[r][c + 3]);
    *reinterpret_cast<ushort4*>(&Bt[(size_t)(n0 + r) * K + k0 + c]) = o;
}

// ---------------------------------------------------------------- MFMA GEMM
// C[M,N] = A[M,K](bf16) @ Bt[N,K](bf16)^T. 128xBN tile, BK=32, 4 waves.
// EPI: 0 = bf16 out; 1 = fp32 + bias; 2 = QKV routing (Q pre-scaled by
// QSCALE); 3 = bf16 split-K partial.
template<int BN, int EPI>
__global__ __launch_bounds__(256) void gemm_bt(const u16* __restrict__ A,
                                               const u16* __restrict__ Bt,
                                               const float* __restrict__ bias,
                                               float* __restrict__ C,
                                               u16* __restrict__ Cb,
                                               u16* __restrict__ Vt,
                                               int M, int N, int K) {
    constexpr int WN = BN / 2;
    constexpr int NT = WN / 16;
    __shared__ u16 As[128 * 32];
    __shared__ u16 Bs[BN * 32];
    const int tid = threadIdx.x;
    const int wave = tid >> 6, lane = tid & 63;
    const int l15 = lane & 15, quad = lane >> 4;
    const int wm = (wave >> 1) * 64, wn = (wave & 1) * WN;
    const int row0 = blockIdx.y * 128, col0 = blockIdx.x * BN;

    int kbase = 0, kend = K;
    if (EPI == 3) {
        int chunk = K / gridDim.z;
        kbase = blockIdx.z * chunk; kend = kbase + chunk;
    }

    f32x4 acc[4][NT];
    #pragma unroll
    for (int mi = 0; mi < 4; ++mi)
        #pragma unroll
        for (int ni = 0; ni < NT; ++ni)
            #pragma unroll
            for (int e = 0; e < 4; ++e) acc[mi][ni][e] = 0.f;

    for (int k0 = kbase; k0 < kend; k0 += 32) {
        #pragma unroll
        for (int idx0 = 0; idx0 < 512 + BN * 4; idx0 += 256) {
            int idx = idx0 + tid;
            if (idx < 512) {
                int r = idx >> 2, ic = (idx & 3) * 8;
                gl_lds16(A + (size_t)(row0 + r) * K + k0 + ic, &As[idx * 8]);
            } else {
                int ib = idx - 512;
                int r = ib >> 2, ic = (ib & 3) * 8;
                gl_lds16(Bt + (size_t)(col0 + r) * K + k0 + ic, &Bs[ib * 8]);
            }
        }
        __syncthreads();

        short8 af[4], bfr[NT];
        #pragma unroll
        for (int mi = 0; mi < 4; ++mi)
            af[mi] = *reinterpret_cast<const short8*>(&As[(wm + mi * 16 + l15) * 32 + quad * 8]);
        #pragma unroll
        for (int ni = 0; ni < NT; ++ni)
            bfr[ni] = *reinterpret_cast<const short8*>(&Bs[(wn + ni * 16 + l15) * 32 + quad * 8]);
        #pragma unroll
        for (int mi = 0; mi < 4; ++mi)
            #pragma unroll
            for (int ni = 0; ni < NT; ++ni)
                acc[mi][ni] = MFMA16(af[mi], bfr[ni], acc[mi][ni]);
        __syncthreads();
    }

    #pragma unroll
    for (int mi = 0; mi < 4; ++mi)
        #pragma unroll
        for (int ni = 0; ni < NT; ++ni) {
            const int cc = col0 + wn + ni * 16 + l15;
            const int rr0 = row0 + wm + mi * 16 + quad * 4;
            if (EPI == 0) {
                #pragma unroll
                for (int r = 0; r < 4; ++r)
                    Cb[(size_t)(rr0 + r) * N + cc] = f2bf(acc[mi][ni][r]);
            } else if (EPI == 1) {
                #pragma unroll
                for (int r = 0; r < 4; ++r)
                    C[(size_t)(rr0 + r) * N + cc] = acc[mi][ni][r] + bias[cc];
            } else if (EPI == 3) {
                u16* Cz = Cb + (size_t)blockIdx.z * M * N;
                #pragma unroll
                for (int r = 0; r < 4; ++r)
                    Cz[(size_t)(rr0 + r) * N + cc] = f2bf(acc[mi][ni][r]);
            } else {  // EPI == 2: QKV routing
                if (cc < 1024) {
                    const bool isq = (cc < 512);
                    size_t base = isq ? (size_t)cc
                                      : ((size_t)MROWS * 512 + cc - 512);
                    const float sc = isq ? QSCALE : 1.f;
                    #pragma unroll
                    for (int r = 0; r < 4; ++r)
                        Cb[base + (size_t)(rr0 + r) * 512] = f2bf(acc[mi][ni][r] * sc);
                } else {
                    int hh = (cc - 1024) >> 6, dd = (cc - 1024) & 63;
                    int bb = rr0 >> 11, srow = rr0 & 2047;
                    ushort4 o;
                    o.x = f2bf(acc[mi][ni][0]); o.y = f2bf(acc[mi][ni][1]);
                    o.z = f2bf(acc[mi][ni][2]); o.w = f2bf(acc[mi][ni][3]);
                    *reinterpret_cast<ushort4*>(
                        &Vt[(((size_t)(bb * 8 + hh) * 64 + dd) << 11) + srow]) = o;
                }
            }
        }
}

// ---------------------------------------------------------------- attention
// Block = (qtile 64, bh, ksplit 4). S^T = K*Q^T (Q pre-scaled); exp'd P feeds
// PV directly from registers via mfma 16x16x16 with v_perm truncating packs.
// O^T transposed via LDS in epilogue. Partials: O bf16, l fp32.
__global__ __launch_bounds__(256) void attn_kernel(const u16* __restrict__ qk_b,
                                                   const u16* __restrict__ vT_b,
                                                   u16* __restrict__ OpartB,
                                                   float* __restrict__ lpart) {
    __shared__ u16 SM[64 * 64 + 2 * 64 * 72];
    u16 (*Qs)[64] = (u16(*)[64])SM;
    u16 (*Ks)[72] = (u16(*)[72])(SM + 64 * 64);
    u16 (*VT)[72] = (u16(*)[72])(SM + 64 * 64 + 64 * 72);

    const int tid = threadIdx.x;
    const int wave = tid >> 6, lane = tid & 63;
    const int l15 = lane & 15, quad = lane >> 4;
    const int qt = blockIdx.x, bh = blockIdx.y, ks = blockIdx.z;
    const int b = bh >> 3, h = bh & 7;
    const int w16 = wave * 16;
    const int r0 = tid >> 3, r1 = r0 + 32;
    const int ch = (tid & 7) * 8;

    // stage Q [64][64]
    {
        const u16* qb = qk_b + (size_t)(b * SEQ + qt * 64) * 512 + h * 64;
        *reinterpret_cast<uint4*>(&Qs[r0][ch]) =
            *reinterpret_cast<const uint4*>(&qb[(size_t)r0 * 512 + ch]);
        *reinterpret_cast<uint4*>(&Qs[r1][ch]) =
            *reinterpret_cast<const uint4*>(&qb[(size_t)r1 * 512 + ch]);
    }
    __syncthreads();

    short8 qf[2];
    qf[0] = *reinterpret_cast<const short8*>(&Qs[w16 + l15][quad * 8]);
    qf[1] = *reinterpret_cast<const short8*>(&Qs[w16 + l15][32 + quad * 8]);

    const u16* kb = qk_b + (size_t)MROWS * 512
                  + (size_t)(b * SEQ + ks * KCHUNK) * 512 + h * 64;
    const u16* vb = vT_b + (size_t)bh * 64 * 2048 + ks * KCHUNK;

    uint4 kr0 = *reinterpret_cast<const uint4*>(&kb[(size_t)r0 * 512 + ch]);
    uint4 kr1 = *reinterpret_cast<const uint4*>(&kb[(size_t)r1 * 512 + ch]);
    uint4 vr0 = *reinterpret_cast<const uint4*>(&vb[(size_t)r0 * 2048 + ch]);
    uint4 vr1 = *reinterpret_cast<const uint4*>(&vb[(size_t)r1 * 2048 + ch]);

#ifdef HAVE_MFMA16K16
    f32x4 oacc[4];
    float lsum = 0.f;
    #pragma unroll
    for (int di = 0; di < 4; ++di)
        #pragma unroll
        for (int e = 0; e < 4; ++e) oacc[di][e] = 0.f;

    for (int kt = 0; kt < KCHUNK / 64; ++kt) {
        *reinterpret_cast<uint4*>(&Ks[r0][ch]) = kr0;
        *reinterpret_cast<uint4*>(&Ks[r1][ch]) = kr1;
        *reinterpret_cast<uint4*>(&VT[r0][ch]) = vr0;
        *reinterpret_cast<uint4*>(&VT[r1][ch]) = vr1;
        __syncthreads();

        if (kt + 1 < KCHUNK / 64) {
            const u16* kb2 = kb + (size_t)(kt + 1) * 64 * 512;
            const u16* vb2 = vb + (kt + 1) * 64;
            kr0 = *reinterpret_cast<const uint4*>(&kb2[(size_t)r0 * 512 + ch]);
            kr1 = *reinterpret_cast<const uint4*>(&kb2[(size_t)r1 * 512 + ch]);
            vr0 = *reinterpret_cast<const uint4*>(&vb2[(size_t)r0 * 2048 + ch]);
            vr1 = *reinterpret_cast<const uint4*>(&vb2[(size_t)r1 * 2048 + ch]);
        }

        f32x4 sacc[4];
        #pragma unroll
        for (int ni = 0; ni < 4; ++ni)
            #pragma unroll
            for (int e = 0; e < 4; ++e) sacc[ni][e] = 0.f;
        #pragma unroll
        for (int ksk = 0; ksk < 2; ++ksk) {
            short8 kf[4];
            #pragma unroll
            for (int ni = 0; ni < 4; ++ni)
                kf[ni] = *reinterpret_cast<const short8*>(
                    &Ks[ni * 16 + l15][ksk * 32 + quad * 8]);
            #pragma unroll
            for (int ni = 0; ni < 4; ++ni)
                sacc[ni] = MFMA16(kf[ni], qf[ksk], sacc[ni]);   // A=K, B=Q^T
        }

        // p = exp2(s); truncate-pack two bf16 per v_perm; feed PV directly
        #pragma unroll
        for (int ni = 0; ni < 4; ++ni) {
            float p0 = exp2f(sacc[ni][0]);
            float p1 = exp2f(sacc[ni][1]);
            float p2 = exp2f(sacc[ni][2]);
            float p3 = exp2f(sacc[ni][3]);
            lsum += (p0 + p1) + (p2 + p3);
            union { short4v v; uint32_t u[2]; } P;
            P.u[0] = __builtin_amdgcn_perm(__float_as_uint(p1),
                                           __float_as_uint(p0), 0x07060302u);
            P.u[1] = __builtin_amdgcn_perm(__float_as_uint(p3),
                                           __float_as_uint(p2), 0x07060302u);
            #pragma unroll
            for (int di = 0; di < 4; ++di) {
                short4v vf = *reinterpret_cast<const short4v*>(
                    &VT[di * 16 + l15][ni * 16 + quad * 4]);
                oacc[di] = MFMA16K16(vf, P.v, oacc[di]);   // O^T += V^T P^T
            }
        }
        __syncthreads();
    }

    lsum += __shfl_xor(lsum, 16);
    lsum += __shfl_xor(lsum, 32);

    const size_t pbase = ((size_t)(ks * 16 + bh) * SEQ + qt * 64);
    if (lane < 16) lpart[pbase + w16 + lane] = lsum;

    // transpose O^T -> row-major bf16 partial via LDS
    float* OTf = (float*)SM;   // [64 d][68 q]
    #pragma unroll
    for (int di = 0; di < 4; ++di)
        #pragma unroll
        for (int r = 0; r < 4; ++r)
            OTf[(di * 16 + quad * 4 + r) * 68 + w16 + l15] = oacc[di][r];
    __syncthreads();

    const int ql = tid >> 2, dseg = (tid & 3) * 16;
    u16 ov[16];
    #pragma unroll
    for (int i = 0; i < 16; ++i) ov[i] = f2bf(OTf[(dseg + i) * 68 + ql]);
    u16* op = &OpartB[(pbase + ql) * 64 + dseg];
    *reinterpret_cast<uint4*>(op)     = *reinterpret_cast<const uint4*>(ov);
    *reinterpret_cast<uint4*>(op + 8) = *reinterpret_cast<const uint4*>(ov + 8);
#else
    // fallback: P via LDS round-trip through Qs (Q pre-scaled upstream)
    f32x4 oacc[4];
    float lsum[4];
    #pragma unroll
    for (int di = 0; di < 4; ++di)
        #pragma unroll
        for (int e = 0; e < 4; ++e) oacc[di][e] = 0.f;
    #pragma unroll
    for (int r = 0; r < 4; ++r) lsum[r] = 0.f;

    for (int kt = 0; kt < KCHUNK / 64; ++kt) {
        *reinterpret_cast<uint4*>(&Ks[r0][ch]) = kr0;
        *reinterpret_cast<uint4*>(&Ks[r1][ch]) = kr1;
        *reinterpret_cast<uint4*>(&VT[r0][ch]) = vr0;
        *reinterpret_cast<uint4*>(&VT[r1][ch]) = vr1;
        __syncthreads();

        if (kt + 1 < KCHUNK / 64) {
            const u16* kb2 = kb + (size_t)(kt + 1) * 64 * 512;
            const u16* vb2 = vb + (kt + 1) * 64;
            kr0 = *reinterpret_cast<const uint4*>(&kb2[(size_t)r0 * 512 + ch]);
            kr1 = *reinterpret_cast<const uint4*>(&kb2[(size_t)r1 * 512 + ch]);
            vr0 = *reinterpret_cast<const uint4*>(&vb2[(size_t)r0 * 2048 + ch]);
            vr1 = *reinterpret_cast<const uint4*>(&vb2[(size_t)r1 * 2048 + ch]);
        }

        f32x4 sacc[4];
        #pragma unroll
        for (int ni = 0; ni < 4; ++ni)
            #pragma unroll
            for (int e = 0; e < 4; ++e) sacc[ni][e] = 0.f;
        #pragma unroll
        for (int ksk = 0; ksk < 2; ++ksk) {
            short8 kf[4];
            #pragma unroll
            for (int ni = 0; ni < 4; ++ni)
                kf[ni] = *reinterpret_cast<const short8*>(
                    &Ks[ni * 16 + l15][ksk * 32 + quad * 8]);
            #pragma unroll
            for (int ni = 0; ni < 4; ++ni)
                sacc[ni] = MFMA16(qf[ksk], kf[ni], sacc[ni]);
        }
        #pragma unroll
        for (int ni = 0; ni < 4; ++ni)
            #pragma unroll
            for (int r = 0; r < 4; ++r) {
                float p = exp2f(sacc[ni][r]);
                lsum[r] += p;
                Qs[w16 + quad * 4 + r][ni * 16 + l15] = f2bf(p);
            }
        #pragma unroll
        for (int ksk = 0; ksk < 2; ++ksk) {
            short8 pf = *reinterpret_cast<const short8*>(
                &Qs[w16 + l15][ksk * 32 + quad * 8]);
            #pragma unroll
            for (int di = 0; di < 4; ++di) {
                short8 vf = *reinterpret_cast<const short8*>(
                    &VT[di * 16 + l15][ksk * 32 + quad * 8]);
                oacc[di] = MFMA16(pf, vf, oacc[di]);
            }
        }
        __syncthreads();
    }

    #pragma unroll
    for (int r = 0; r < 4; ++r) {
        float v = lsum[r];
        v += __shfl_xor(v, 1); v += __shfl_xor(v, 2);
        v += __shfl_xor(v, 4); v += __shfl_xor(v, 8);
        lsum[r] = v;
    }
    const size_t pbase = ((size_t)(ks * 16 + bh) * SEQ + qt * 64);
    #pragma unroll
    for (int di = 0; di < 4; ++di)
        #pragma unroll
        for (int r = 0; r < 4; ++r)
            OpartB[(pbase + w16 + quad * 4 + r) * 64 + di * 16 + l15] = f2bf(oacc[di][r]);
    if (l15 == 0)
        #pragma unroll
        for (int r = 0; r < 4; ++r)
            lpart[pbase + w16 + quad * 4 + r] = lsum[r];
#endif
}

// combine: attn_b[row][h*64+d] = (sum_ks O) / (sum_ks l), 4 partials
__global__ void attn_combine_kernel(const u16* __restrict__ OpartB,
                                    const float* __restrict__ lpart,
                                    u16* __restrict__ attn_b) {
    int i = blockIdx.x * 256 + threadIdx.x;     // ushort4 index
    int e = i * 4;
    int row = e >> 9;
    int c = e & 511;
    int h = c >> 6, d = c & 63;
    int b = row >> 11, srow = row & 2047;
    int bh = b * 8 + h;

    float ax = 0.f, ay = 0.f, az = 0.f, aw = 0.f, l = 0.f;
    #pragma unroll
    for (int ks = 0; ks < KSPLIT; ++ks) {
        size_t pk = (size_t)(ks * 16 + bh) * SEQ + srow;
        ushort4 o = *reinterpret_cast<const ushort4*>(&OpartB[pk * 64 + d]);
        ax += bf2f(o.x); ay += bf2f(o.y); az += bf2f(o.z); aw += bf2f(o.w);
        l += lpart[pk];
    }
    float li = 1.f / l;
    ushort4 o;
    o.x = f2bf(ax * li); o.y = f2bf(ay * li);
    o.z = f2bf(az * li); o.w = f2bf(aw * li);
    *reinterpret_cast<ushort4*>(&attn_b[(size_t)row * INNER + c]) = o;
}

// ---------------------------------------------------------------- layernorm
// One wave per row (512 cols = 8/lane), shuffle-only reduction, no barriers.
template<bool A16, bool S16, bool TWO>
__global__ __launch_bounds__(256) void ln_kernel(const void* __restrict__ a_,
                                                 const void* __restrict__ s0_,
                                                 const void* __restrict__ s1_,
                                                 const float* __restrict__ g,
                                                 const float* __restrict__ be,
                                                 float* __restrict__ out32,
                                                 u16* __restrict__ out16) {
    const int tid = threadIdx.x, wave = tid >> 6, lane = tid & 63;
    const int row = blockIdx.x * 4 + wave;
    const size_t off = (size_t)row * INNER;

    float v[8];
    #pragma unroll
    for (int j = 0; j < 2; ++j) {
        const int c = j * 256 + lane * 4;
        float a0, a1, a2, a3;
        if (A16) {
            ushort4 u = *reinterpret_cast<const ushort4*>((const u16*)a_ + off + c);
            a0 = bf2f(u.x); a1 = bf2f(u.y); a2 = bf2f(u.z); a3 = bf2f(u.w);
        } else {
            float4 u = *reinterpret_cast<const float4*>((const float*)a_ + off + c);
            a0 = u.x; a1 = u.y; a2 = u.z; a3 = u.w;
        }
        float s0, s1, s2, s3;
        if (S16) {
            ushort4 u = *reinterpret_cast<const ushort4*>((const u16*)s0_ + off + c);
            s0 = bf2f(u.x); s1 = bf2f(u.y); s2 = bf2f(u.z); s3 = bf2f(u.w);
        } else {
            float4 u = *reinterpret_cast<const float4*>((const float*)s0_ + off + c);
            s0 = u.x; s1 = u.y; s2 = u.z; s3 = u.w;
        }
        v[j*4+0] = a0 + s0; v[j*4+1] = a1 + s1; v[j*4+2] = a2 + s2; v[j*4+3] = a3 + s3;
        if (TWO) {
            if (S16) {
                ushort4 u = *reinterpret_cast<const ushort4*>((const u16*)s1_ + off + c);
                v[j*4+0] += bf2f(u.x); v[j*4+1] += bf2f(u.y);
                v[j*4+2] += bf2f(u.z); v[j*4+3] += bf2f(u.w);
            } else {
                float4 u = *reinterpret_cast<const float4*>((const float*)s1_ + off + c);
                v[j*4+0] += u.x; v[j*4+1] += u.y; v[j*4+2] += u.z; v[j*4+3] += u.w;
            }
        }
    }

    float s = 0.f;
    #pragma unroll
    for (int i = 0; i < 8; ++i) s += v[i];
    #pragma unroll
    for (int m = 1; m < 64; m <<= 1) s += __shfl_xor(s, m);
    const float mu = s * (1.f / INNER);

    float q = 0.f;
    #pragma unroll
    for (int i = 0; i < 8; ++i) { v[i] -= mu; q += v[i] * v[i]; }
    #pragma unroll
    for (int m = 1; m < 64; m <<= 1) q += __shfl_xor(q, m);
    const float rstd = rsqrtf(q * (1.f / INNER) + LN_EPS);

    #pragma unroll
    for (int j = 0; j < 2; ++j) {
        const int c = j * 256 + lane * 4;
        float4 gv = *reinterpret_cast<const float4*>(g + c);
        float4 bv = *reinterpret_cast<const float4*>(be + c);
        float y0 = v[j*4+0] * rstd * gv.x + bv.x;
        float y1 = v[j*4+1] * rstd * gv.y + bv.y;
        float y2 = v[j*4+2] * rstd * gv.z + bv.z;
        float y3 = v[j*4+3] * rstd * gv.w + bv.w;
        if (out32) {
            float4 o = {y0, y1, y2, y3};
            *reinterpret_cast<float4*>(out32 + off + c) = o;
        }
        if (out16) {
            ushort4 o;
            o.x = f2bf(y0); o.y = f2bf(y1); o.z = f2bf(y2); o.w = f2bf(y3);
            *reinterpret_cast<ushort4*>(out16 + off + c) = o;
        }
    }
}

// ---------------------------------------------------------------- launch
extern "C" void kernel_launch(void* const* d_in, const int* in_sizes, int n_in,
                              void* d_out, int out_size, void* d_ws, size_t ws_size,
                              hipStream_t stream) {
    const float* x     = (const float*)d_in[0];
    const float* w_qkv = (const float*)d_in[1];
    const float* w_out = (const float*)d_in[2];
    const float* b_out = (const float*)d_in[3];
    const float* w_ff1 = (const float*)d_in[4];
    const float* w_ff2 = (const float*)d_in[5];
    const float* g1    = (const float*)d_in[6];
    const float* be1   = (const float*)d_in[7];
    const float* g2    = (const float*)d_in[8];
    const float* be2   = (const float*)d_in[9];
    float* out = (float*)d_out;

    char* W = (char*)d_ws;
    // Phases: A prep, B qkv, C attn, D combine, E proj, F LN1, G ff1, H ff2, I LN2
    u16*   w_outT     = (u16*)  (W + 0);          // 0.52 [A->E]
    u16*   w_ff1T     = (u16*)  (W + 524288);     // 2.10 [A->G]
    u16*   w_ff2T     = (u16*)  (W + 2621440);    // 2.10 [A->H]
    u16*   qk_b       = (u16*)  (W + 4718592);    // 8.39 (q then k) [B->C]
    float* proj       = (float*)(W + 4718592);    // 8.39 [E->F] (reuse qk_b)
    u16*   ff2p       = (u16*)  (W + 4718592);    // 8.39 (2 bf16 partials) [H->I]
    u16*   vT_b       = (u16*)  (W + 13107200);   // 4.19 [B->C]
    u16*   attn_res_b = (u16*)  (W + 13107200);   // 4.19 [F->I] (reuse vT_b)
    u16*   x_b        = (u16*)  (W + 17301504);   // 4.19 [A->B]
    u16*   w_qkvT     = (u16*)  (W + 21495808);   // 1.57 [A->B]
    u16*   OpartB     = (u16*)  (W + 17301504);   // 16.78 [C->D] (reuse x_b+w_qkvT)
    u16*   ff1_b      = (u16*)  (W + 17301504);   // 16.78 [G->H] (reuse OpartB)
    float* lpart      = (float*)(W + 34078720);   // 0.52 [C->D]
    u16*   attn_b     = (u16*)  (W + 34603008);   // 4.19 [D->E]  ends 38797312

    // A) fused prep: x->bf16 + 4 weight transposes (5120 blocks)
    prep_kernel<<<5120, 256, 0, stream>>>(x, x_b, w_qkv, w_qkvT, w_out, w_outT,
                                          w_ff1, w_ff1T, w_ff2, w_ff2T);

    // B) qkv = x @ w_qkv -> q(pre-scaled)/k rowmajor, V transposed (768 blocks)
    gemm_bt<64, 2><<<dim3(1536 / 64, MROWS / 128), 256, 0, stream>>>(
        x_b, w_qkvT, nullptr, nullptr, qk_b, vT_b, MROWS, 1536, INNER);

    // C) attention partials (2048 blocks)
    attn_kernel<<<dim3(SEQ / 64, BATCH * HEADS, KSPLIT), 256, 0, stream>>>(
        qk_b, vT_b, OpartB, lpart);

    // D) combine -> bf16 (1024 blocks)
    attn_combine_kernel<<<(MROWS * INNER / 4) / 256, 256, 0, stream>>>(
        OpartB, lpart, attn_b);

    // E) proj = attn @ w_out + b_out -> fp32 (256 blocks)
    gemm_bt<64, 1><<<dim3(INNER / 64, MROWS / 128), 256, 0, stream>>>(
        attn_b, w_outT, b_out, proj, nullptr, nullptr, MROWS, INNER, INNER);

    // F) attn_res = LN(x + proj) -> bf16
    ln_kernel<false, false, false><<<MROWS / 4, 256, 0, stream>>>(
        x, proj, nullptr, g1, be1, nullptr, attn_res_b);

    // G) ff1 = attn_res @ w_ff1 -> bf16 (512 blocks)
    gemm_bt<128, 0><<<dim3(2048 / 128, MROWS / 128), 256, 0, stream>>>(
        attn_res_b, w_ff1T, nullptr, nullptr, ff1_b, nullptr, MROWS, 2048, INNER);

    // H) ff2 partials = ff1 @ w_ff2 (split-K=2) -> bf16 x2 (512 blocks)
    gemm_bt<64, 3><<<dim3(INNER / 64, MROWS / 128, 2), 256, 0, stream>>>(
        ff1_b, w_ff2T, nullptr, nullptr, ff2p, nullptr, MROWS, INNER, 2048);

    // I) out = LN(attn_res + ff2p0 + ff2p1) -> fp32 d_out
    ln_kernel<true, true, true><<<MROWS / 4, 256, 0, stream>>>(
        attn_res_b, ff2p, ff2p + (size_t)MROWS * INNER, g2, be2, out, nullptr);
}

// Round 9
// 206.770 us; speedup vs baseline: 1.1275x; 1.0204x over previous
//
#include <hip/hip_runtime.h>
#include <hip/hip_bf16.h>
#include <cstdint>
#include <cstddef>
#include <math.h>

#define HEADS 8
#define DHEAD 64
#define INNER 512
#define BATCH 2
#define SEQ   2048
#define MROWS (BATCH*SEQ)   /* 4096 */
#define LN_EPS 1e-6f
#define KSPLIT 4
#define KCHUNK (SEQ/KSPLIT) /* 512 */
#define QSCALE 0.18033688011110918f   /* 0.125 * log2(e), folded into Q */

typedef unsigned short u16;
typedef __attribute__((ext_vector_type(8))) short short8;
typedef __attribute__((ext_vector_type(4))) short short4v;
typedef __attribute__((ext_vector_type(4))) float f32x4;

#define MFMA16(a,b,c) __builtin_amdgcn_mfma_f32_16x16x32_bf16((a),(b),(c),0,0,0)
#if __has_builtin(__builtin_amdgcn_mfma_f32_16x16x16bf16_1k)
#define HAVE_MFMA16K16 1
#define MFMA16K16(a,b,c) __builtin_amdgcn_mfma_f32_16x16x16bf16_1k((a),(b),(c),0,0,0)
#endif

__device__ __forceinline__ float bf2f(u16 u) {
    union { float f; uint32_t i; } x; x.i = ((uint32_t)u) << 16; return x.f;
}
__device__ __forceinline__ u16 f2bf(float f) {
    __hip_bfloat16 h = __float2bfloat16(f);   // RNE
    return *reinterpret_cast<u16*>(&h);
}
__device__ __forceinline__ void gl_lds16(const void* g, void* l) {
    __builtin_amdgcn_global_load_lds(
        (const __attribute__((address_space(1))) void*)g,
        (__attribute__((address_space(3))) void*)l, 16, 0, 0);
}

// ---------------------------------------------------------------- prep
__global__ void prep_kernel(const float* __restrict__ x, u16* __restrict__ x_b,
                            const float* __restrict__ w_qkv, u16* __restrict__ w_qkvT,
                            const float* __restrict__ w_out, u16* __restrict__ w_outT,
                            const float* __restrict__ w_ff1, u16* __restrict__ w_ff1T,
                            const float* __restrict__ w_ff2, u16* __restrict__ w_ff2T) {
    __shared__ float T[32][33];
    const int blk = blockIdx.x, tid = threadIdx.x;
    if (blk < 2048) {
        int i = blk * 256 + tid;
        float4 v = reinterpret_cast<const float4*>(x)[i];
        ushort4 o;
        o.x = f2bf(v.x); o.y = f2bf(v.y); o.z = f2bf(v.z); o.w = f2bf(v.w);
        reinterpret_cast<ushort4*>(x_b)[i] = o;
        return;
    }
    const float* B; u16* Bt; int K, N, t;
    if (blk < 2816)      { B = w_qkv; Bt = w_qkvT; K = 512;  N = 1536; t = blk - 2048; }
    else if (blk < 3072) { B = w_out; Bt = w_outT; K = 512;  N = 512;  t = blk - 2816; }
    else if (blk < 4096) { B = w_ff1; Bt = w_ff1T; K = 512;  N = 2048; t = blk - 3072; }
    else                 { B = w_ff2; Bt = w_ff2T; K = 2048; N = 512;  t = blk - 4096; }
    const int nb = N / 32;
    const int n0 = (t % nb) * 32, k0 = (t / nb) * 32;
    const int r = tid >> 3, c = (tid & 7) * 4;
    float4 v = *reinterpret_cast<const float4*>(&B[(size_t)(k0 + r) * N + n0 + c]);
    T[c + 0][r] = v.x; T[c + 1][r] = v.y; T[c + 2][r] = v.z; T[c + 3][r] = v.w;
    __syncthreads();
    ushort4 o;
    o.x = f2bf(T[r][c + 0]); o.y = f2bf(T[r][c + 1]);
    o.z = f2bf(T[r][c + 2]); o.w = f2bf(T[r][c + 3]);
    *reinterpret_cast<ushort4*>(&Bt[(size_t)(n0 + r) * K + k0 + c]) = o;
}

// ---------------------------------------------------------------- MFMA GEMM
// C[M,N] = A[M,K](bf16) @ Bt[N,K](bf16)^T. 128xBN tile, BK-deep k-steps,
// 4 waves. EPI: 0 bf16 out; 1 fp32+bias; 2 QKV routing; 3 bf16 split-K.
template<int BN, int BK, int EPI>
__global__ __launch_bounds__(256) void gemm_bt(const u16* __restrict__ A,
                                               const u16* __restrict__ Bt,
                                               const float* __restrict__ bias,
                                               float* __restrict__ C,
                                               u16* __restrict__ Cb,
                                               u16* __restrict__ Vt,
                                               int M, int N, int K) {
    constexpr int WN = BN / 2;
    constexpr int NT = WN / 16;
    constexpr int ACH = 128 * BK / 8;   // A 16B-chunks per k-step
    constexpr int BCH = BN * BK / 8;
    constexpr int CW = BK / 8;          // chunks per row
    __shared__ u16 As[128 * BK];
    __shared__ u16 Bs[BN * BK];
    const int tid = threadIdx.x;
    const int wave = tid >> 6, lane = tid & 63;
    const int l15 = lane & 15, quad = lane >> 4;
    const int wm = (wave >> 1) * 64, wn = (wave & 1) * WN;
    const int row0 = blockIdx.y * 128, col0 = blockIdx.x * BN;

    int kbase = 0, kend = K;
    if (EPI == 3) {
        int chunk = K / gridDim.z;
        kbase = blockIdx.z * chunk; kend = kbase + chunk;
    }

    f32x4 acc[4][NT];
    #pragma unroll
    for (int mi = 0; mi < 4; ++mi)
        #pragma unroll
        for (int ni = 0; ni < NT; ++ni)
            #pragma unroll
            for (int e = 0; e < 4; ++e) acc[mi][ni][e] = 0.f;

    for (int k0 = kbase; k0 < kend; k0 += BK) {
        #pragma unroll
        for (int idx0 = 0; idx0 < ACH + BCH; idx0 += 256) {
            int idx = idx0 + tid;
            if (idx < ACH) {
                int r = idx / CW, ic = (idx % CW) * 8;
                gl_lds16(A + (size_t)(row0 + r) * K + k0 + ic, &As[idx * 8]);
            } else {
                int ib = idx - ACH;
                int r = ib / CW, ic = (ib % CW) * 8;
                gl_lds16(Bt + (size_t)(col0 + r) * K + k0 + ic, &Bs[ib * 8]);
            }
        }
        __syncthreads();

        #pragma unroll
        for (int ks2 = 0; ks2 < BK / 32; ++ks2) {
            short8 af[4], bfr[NT];
            #pragma unroll
            for (int mi = 0; mi < 4; ++mi)
                af[mi] = *reinterpret_cast<const short8*>(
                    &As[(wm + mi * 16 + l15) * BK + ks2 * 32 + quad * 8]);
            #pragma unroll
            for (int ni = 0; ni < NT; ++ni)
                bfr[ni] = *reinterpret_cast<const short8*>(
                    &Bs[(wn + ni * 16 + l15) * BK + ks2 * 32 + quad * 8]);
            #pragma unroll
            for (int mi = 0; mi < 4; ++mi)
                #pragma unroll
                for (int ni = 0; ni < NT; ++ni)
                    acc[mi][ni] = MFMA16(af[mi], bfr[ni], acc[mi][ni]);
        }
        __syncthreads();
    }

    #pragma unroll
    for (int mi = 0; mi < 4; ++mi)
        #pragma unroll
        for (int ni = 0; ni < NT; ++ni) {
            const int cc = col0 + wn + ni * 16 + l15;
            const int rr0 = row0 + wm + mi * 16 + quad * 4;
            if (EPI == 0) {
                #pragma unroll
                for (int r = 0; r < 4; ++r)
                    Cb[(size_t)(rr0 + r) * N + cc] = f2bf(acc[mi][ni][r]);
            } else if (EPI == 1) {
                #pragma unroll
                for (int r = 0; r < 4; ++r)
                    C[(size_t)(rr0 + r) * N + cc] = acc[mi][ni][r] + bias[cc];
            } else if (EPI == 3) {
                u16* Cz = Cb + (size_t)blockIdx.z * M * N;
                #pragma unroll
                for (int r = 0; r < 4; ++r)
                    Cz[(size_t)(rr0 + r) * N + cc] = f2bf(acc[mi][ni][r]);
            } else {  // EPI == 2: QKV routing
                if (cc < 1024) {
                    const bool isq = (cc < 512);
                    size_t base = isq ? (size_t)cc
                                      : ((size_t)MROWS * 512 + cc - 512);
                    const float sc = isq ? QSCALE : 1.f;
                    #pragma unroll
                    for (int r = 0; r < 4; ++r)
                        Cb[base + (size_t)(rr0 + r) * 512] = f2bf(acc[mi][ni][r] * sc);
                } else {
                    int hh = (cc - 1024) >> 6, dd = (cc - 1024) & 63;
                    int bb = rr0 >> 11, srow = rr0 & 2047;
                    ushort4 o;
                    o.x = f2bf(acc[mi][ni][0]); o.y = f2bf(acc[mi][ni][1]);
                    o.z = f2bf(acc[mi][ni][2]); o.w = f2bf(acc[mi][ni][3]);
                    *reinterpret_cast<ushort4*>(
                        &Vt[(((size_t)(bb * 8 + hh) * 64 + dd) << 11) + srow]) = o;
                }
            }
        }
}

// ---------------------------------------------------------------- attention
// Block = (qtile 128 = 2x64, bh, ksplit 4): 1024 blocks, 4/CU co-resident.
// Two Q-tiles share each K/V staging + barrier. S^T = K*Q^T (Q pre-scaled);
// exp'd P feeds PV from registers (mfma 16x16x16, v_perm packs).
__global__ __launch_bounds__(256) void attn_kernel(const u16* __restrict__ qk_b,
                                                   const u16* __restrict__ vT_b,
                                                   u16* __restrict__ OpartB,
                                                   float* __restrict__ lpart) {
    __shared__ u16 SM[2 * 64 * 64 + 2 * 64 * 72];   // 34816 B
    u16 (*Qs)[64] = (u16(*)[64])SM;                 // [128][64] (2 tiles)
    u16 (*Ks)[72] = (u16(*)[72])(SM + 2 * 64 * 64);
    u16 (*VT)[72] = (u16(*)[72])(SM + 2 * 64 * 64 + 64 * 72);

    const int tid = threadIdx.x;
    const int wave = tid >> 6, lane = tid & 63;
    const int l15 = lane & 15, quad = lane >> 4;
    const int qt = blockIdx.x, bh = blockIdx.y, ks = blockIdx.z;
    const int b = bh >> 3, h = bh & 7;
    const int w16 = wave * 16;
    const int r0 = tid >> 3, r1 = r0 + 32;
    const int ch = (tid & 7) * 8;

    // stage both Q tiles [128][64]
    {
        const u16* qb = qk_b + (size_t)(b * SEQ + qt * 128) * 512 + h * 64;
        #pragma unroll
        for (int j = 0; j < 4; ++j) {
            int idx = tid + j * 256;
            int r = idx >> 3, c = (idx & 7) * 8;
            *reinterpret_cast<uint4*>(&Qs[r][c]) =
                *reinterpret_cast<const uint4*>(&qb[(size_t)r * 512 + c]);
        }
    }
    __syncthreads();

    short8 qf[2][2];
    #pragma unroll
    for (int t = 0; t < 2; ++t) {
        qf[t][0] = *reinterpret_cast<const short8*>(&Qs[t * 64 + w16 + l15][quad * 8]);
        qf[t][1] = *reinterpret_cast<const short8*>(&Qs[t * 64 + w16 + l15][32 + quad * 8]);
    }

    const u16* kb = qk_b + (size_t)MROWS * 512
                  + (size_t)(b * SEQ + ks * KCHUNK) * 512 + h * 64;
    const u16* vb = vT_b + (size_t)bh * 64 * 2048 + ks * KCHUNK;

    uint4 kr0 = *reinterpret_cast<const uint4*>(&kb[(size_t)r0 * 512 + ch]);
    uint4 kr1 = *reinterpret_cast<const uint4*>(&kb[(size_t)r1 * 512 + ch]);
    uint4 vr0 = *reinterpret_cast<const uint4*>(&vb[(size_t)r0 * 2048 + ch]);
    uint4 vr1 = *reinterpret_cast<const uint4*>(&vb[(size_t)r1 * 2048 + ch]);

#ifdef HAVE_MFMA16K16
    f32x4 oacc[2][4];
    float lsum[2] = {0.f, 0.f};
    #pragma unroll
    for (int t = 0; t < 2; ++t)
        #pragma unroll
        for (int di = 0; di < 4; ++di)
            #pragma unroll
            for (int e = 0; e < 4; ++e) oacc[t][di][e] = 0.f;

    for (int kt = 0; kt < KCHUNK / 64; ++kt) {
        *reinterpret_cast<uint4*>(&Ks[r0][ch]) = kr0;
        *reinterpret_cast<uint4*>(&Ks[r1][ch]) = kr1;
        *reinterpret_cast<uint4*>(&VT[r0][ch]) = vr0;
        *reinterpret_cast<uint4*>(&VT[r1][ch]) = vr1;
        __syncthreads();

        if (kt + 1 < KCHUNK / 64) {
            const u16* kb2 = kb + (size_t)(kt + 1) * 64 * 512;
            const u16* vb2 = vb + (kt + 1) * 64;
            kr0 = *reinterpret_cast<const uint4*>(&kb2[(size_t)r0 * 512 + ch]);
            kr1 = *reinterpret_cast<const uint4*>(&kb2[(size_t)r1 * 512 + ch]);
            vr0 = *reinterpret_cast<const uint4*>(&vb2[(size_t)r0 * 2048 + ch]);
            vr1 = *reinterpret_cast<const uint4*>(&vb2[(size_t)r1 * 2048 + ch]);
        }

        short8 kf[4];
        #pragma unroll
        for (int ni = 0; ni < 4; ++ni)
            kf[ni] = *reinterpret_cast<const short8*>(&Ks[ni * 16 + l15][quad * 8]);
        short8 kf2[4];
        #pragma unroll
        for (int ni = 0; ni < 4; ++ni)
            kf2[ni] = *reinterpret_cast<const short8*>(&Ks[ni * 16 + l15][32 + quad * 8]);

        #pragma unroll
        for (int t = 0; t < 2; ++t) {
            f32x4 sacc[4];
            #pragma unroll
            for (int ni = 0; ni < 4; ++ni)
                #pragma unroll
                for (int e = 0; e < 4; ++e) sacc[ni][e] = 0.f;
            #pragma unroll
            for (int ni = 0; ni < 4; ++ni)
                sacc[ni] = MFMA16(kf[ni], qf[t][0], sacc[ni]);
            #pragma unroll
            for (int ni = 0; ni < 4; ++ni)
                sacc[ni] = MFMA16(kf2[ni], qf[t][1], sacc[ni]);

            #pragma unroll
            for (int ni = 0; ni < 4; ++ni) {
                float p0 = exp2f(sacc[ni][0]);
                float p1 = exp2f(sacc[ni][1]);
                float p2 = exp2f(sacc[ni][2]);
                float p3 = exp2f(sacc[ni][3]);
                lsum[t] += (p0 + p1) + (p2 + p3);
                union { short4v v; uint32_t u[2]; } P;
                P.u[0] = __builtin_amdgcn_perm(__float_as_uint(p1),
                                               __float_as_uint(p0), 0x07060302u);
                P.u[1] = __builtin_amdgcn_perm(__float_as_uint(p3),
                                               __float_as_uint(p2), 0x07060302u);
                #pragma unroll
                for (int di = 0; di < 4; ++di) {
                    short4v vf = *reinterpret_cast<const short4v*>(
                        &VT[di * 16 + l15][ni * 16 + quad * 4]);
                    oacc[t][di] = MFMA16K16(vf, P.v, oacc[t][di]);  // O^T += V^T P^T
                }
            }
        }
        __syncthreads();
    }

    #pragma unroll
    for (int t = 0; t < 2; ++t) {
        lsum[t] += __shfl_xor(lsum[t], 16);
        lsum[t] += __shfl_xor(lsum[t], 32);
    }

    const size_t pbase = ((size_t)(ks * 16 + bh) * SEQ + qt * 128);
    if (lane < 16) {
        lpart[pbase + w16 + lane] = lsum[0];
        lpart[pbase + 64 + w16 + lane] = lsum[1];
    }

    // transpose O^T -> row-major bf16 partials via LDS (one tile at a time)
    float* OTf = (float*)SM;   // [64 d][68 q] = 17408 B, fits in SM
    const int ql = tid >> 2, dseg = (tid & 3) * 16;
    #pragma unroll
    for (int t = 0; t < 2; ++t) {
        __syncthreads();
        #pragma unroll
        for (int di = 0; di < 4; ++di)
            #pragma unroll
            for (int r = 0; r < 4; ++r)
                OTf[(di * 16 + quad * 4 + r) * 68 + w16 + l15] = oacc[t][di][r];
        __syncthreads();
        u16 ov[16];
        #pragma unroll
        for (int i = 0; i < 16; ++i) ov[i] = f2bf(OTf[(dseg + i) * 68 + ql]);
        u16* op = &OpartB[(pbase + t * 64 + ql) * 64 + dseg];
        *reinterpret_cast<uint4*>(op)     = *reinterpret_cast<const uint4*>(ov);
        *reinterpret_cast<uint4*>(op + 8) = *reinterpret_cast<const uint4*>(ov + 8);
    }
#else
    // fallback: per-tile P round-trip through Qs (wave-private rows)
    f32x4 oacc[2][4];
    float lsum[2][4];
    #pragma unroll
    for (int t = 0; t < 2; ++t)
        #pragma unroll
        for (int di = 0; di < 4; ++di) {
            #pragma unroll
            for (int e = 0; e < 4; ++e) oacc[t][di][e] = 0.f;
            lsum[t][di] = 0.f;
        }

    for (int kt = 0; kt < KCHUNK / 64; ++kt) {
        *reinterpret_cast<uint4*>(&Ks[r0][ch]) = kr0;
        *reinterpret_cast<uint4*>(&Ks[r1][ch]) = kr1;
        *reinterpret_cast<uint4*>(&VT[r0][ch]) = vr0;
        *reinterpret_cast<uint4*>(&VT[r1][ch]) = vr1;
        __syncthreads();

        if (kt + 1 < KCHUNK / 64) {
            const u16* kb2 = kb + (size_t)(kt + 1) * 64 * 512;
            const u16* vb2 = vb + (kt + 1) * 64;
            kr0 = *reinterpret_cast<const uint4*>(&kb2[(size_t)r0 * 512 + ch]);
            kr1 = *reinterpret_cast<const uint4*>(&kb2[(size_t)r1 * 512 + ch]);
            vr0 = *reinterpret_cast<const uint4*>(&vb2[(size_t)r0 * 2048 + ch]);
            vr1 = *reinterpret_cast<const uint4*>(&vb2[(size_t)r1 * 2048 + ch]);
        }

        #pragma unroll
        for (int t = 0; t < 2; ++t) {
            f32x4 sacc[4];
            #pragma unroll
            for (int ni = 0; ni < 4; ++ni)
                #pragma unroll
                for (int e = 0; e < 4; ++e) sacc[ni][e] = 0.f;
            #pragma unroll
            for (int ksk = 0; ksk < 2; ++ksk) {
                short8 kf[4];
                #pragma unroll
                for (int ni = 0; ni < 4; ++ni)
                    kf[ni] = *reinterpret_cast<const short8*>(
                        &Ks[ni * 16 + l15][ksk * 32 + quad * 8]);
                #pragma unroll
                for (int ni = 0; ni < 4; ++ni)
                    sacc[ni] = MFMA16(qf[t][ksk], kf[ni], sacc[ni]);
            }
            #pragma unroll
            for (int ni = 0; ni < 4; ++ni)
                #pragma unroll
                for (int r = 0; r < 4; ++r) {
                    float p = exp2f(sacc[ni][r]);
                    lsum[t][r] += p;
                    Qs[t * 64 + w16 + quad * 4 + r][ni * 16 + l15] = f2bf(p);
                }
            #pragma unroll
            for (int ksk = 0; ksk < 2; ++ksk) {
                short8 pf = *reinterpret_cast<const short8*>(
                    &Qs[t * 64 + w16 + l15][ksk * 32 + quad * 8]);
                #pragma unroll
                for (int di = 0; di < 4; ++di) {
                    short8 vf = *reinterpret_cast<const short8*>(
                        &VT[di * 16 + l15][ksk * 32 + quad * 8]);
                    oacc[t][di] = MFMA16(pf, vf, oacc[t][di]);
                }
            }
        }
        __syncthreads();
    }

    const size_t pbase = ((size_t)(ks * 16 + bh) * SEQ + qt * 128);
    #pragma unroll
    for (int t = 0; t < 2; ++t) {
        #pragma unroll
        for (int r = 0; r < 4; ++r) {
            float v = lsum[t][r];
            v += __shfl_xor(v, 1); v += __shfl_xor(v, 2);
            v += __shfl_xor(v, 4); v += __shfl_xor(v, 8);
            lsum[t][r] = v;
        }
        #pragma unroll
        for (int di = 0; di < 4; ++di)
            #pragma unroll
            for (int r = 0; r < 4; ++r)
                OpartB[(pbase + t * 64 + w16 + quad * 4 + r) * 64 + di * 16 + l15]
                    = f2bf(oacc[t][di][r]);
        if (l15 == 0)
            #pragma unroll
            for (int r = 0; r < 4; ++r)
                lpart[pbase + t * 64 + w16 + quad * 4 + r] = lsum[t][r];
    }
#endif
}

// combine: attn_b[row][h*64+d] = (sum_ks O) / (sum_ks l), 4 partials
__global__ void attn_combine_kernel(const u16* __restrict__ OpartB,
                                    const float* __restrict__ lpart,
                                    u16* __restrict__ attn_b) {
    int i = blockIdx.x * 256 + threadIdx.x;     // ushort4 index
    int e = i * 4;
    int row = e >> 9;
    int c = e & 511;
    int h = c >> 6, d = c & 63;
    int b = row >> 11, srow = row & 2047;
    int bh = b * 8 + h;

    float ax = 0.f, ay = 0.f, az = 0.f, aw = 0.f, l = 0.f;
    #pragma unroll
    for (int ks = 0; ks < KSPLIT; ++ks) {
        size_t pk = (size_t)(ks * 16 + bh) * SEQ + srow;
        ushort4 o = *reinterpret_cast<const ushort4*>(&OpartB[pk * 64 + d]);
        ax += bf2f(o.x); ay += bf2f(o.y); az += bf2f(o.z); aw += bf2f(o.w);
        l += lpart[pk];
    }
    float li = 1.f / l;
    ushort4 o;
    o.x = f2bf(ax * li); o.y = f2bf(ay * li);
    o.z = f2bf(az * li); o.w = f2bf(aw * li);
    *reinterpret_cast<ushort4*>(&attn_b[(size_t)row * INNER + c]) = o;
}

// ---------------------------------------------------------------- layernorm
// One wave per row (512 cols = 8/lane), shuffle-only reduction, no barriers.
template<bool A16, bool S16, bool TWO>
__global__ __launch_bounds__(256) void ln_kernel(const void* __restrict__ a_,
                                                 const void* __restrict__ s0_,
                                                 const void* __restrict__ s1_,
                                                 const float* __restrict__ g,
                                                 const float* __restrict__ be,
                                                 float* __restrict__ out32,
                                                 u16* __restrict__ out16) {
    const int tid = threadIdx.x, wave = tid >> 6, lane = tid & 63;
    const int row = blockIdx.x * 4 + wave;
    const size_t off = (size_t)row * INNER;

    float v[8];
    #pragma unroll
    for (int j = 0; j < 2; ++j) {
        const int c = j * 256 + lane * 4;
        float a0, a1, a2, a3;
        if (A16) {
            ushort4 u = *reinterpret_cast<const ushort4*>((const u16*)a_ + off + c);
            a0 = bf2f(u.x); a1 = bf2f(u.y); a2 = bf2f(u.z); a3 = bf2f(u.w);
        } else {
            float4 u = *reinterpret_cast<const float4*>((const float*)a_ + off + c);
            a0 = u.x; a1 = u.y; a2 = u.z; a3 = u.w;
        }
        float s0, s1, s2, s3;
        if (S16) {
            ushort4 u = *reinterpret_cast<const ushort4*>((const u16*)s0_ + off + c);
            s0 = bf2f(u.x); s1 = bf2f(u.y); s2 = bf2f(u.z); s3 = bf2f(u.w);
        } else {
            float4 u = *reinterpret_cast<const float4*>((const float*)s0_ + off + c);
            s0 = u.x; s1 = u.y; s2 = u.z; s3 = u.w;
        }
        v[j*4+0] = a0 + s0; v[j*4+1] = a1 + s1; v[j*4+2] = a2 + s2; v[j*4+3] = a3 + s3;
        if (TWO) {
            if (S16) {
                ushort4 u = *reinterpret_cast<const ushort4*>((const u16*)s1_ + off + c);
                v[j*4+0] += bf2f(u.x); v[j*4+1] += bf2f(u.y);
                v[j*4+2] += bf2f(u.z); v[j*4+3] += bf2f(u.w);
            } else {
                float4 u = *reinterpret_cast<const float4*>((const float*)s1_ + off + c);
                v[j*4+0] += u.x; v[j*4+1] += u.y; v[j*4+2] += u.z; v[j*4+3] += u.w;
            }
        }
    }

    float s = 0.f;
    #pragma unroll
    for (int i = 0; i < 8; ++i) s += v[i];
    #pragma unroll
    for (int m = 1; m < 64; m <<= 1) s += __shfl_xor(s, m);
    const float mu = s * (1.f / INNER);

    float q = 0.f;
    #pragma unroll
    for (int i = 0; i < 8; ++i) { v[i] -= mu; q += v[i] * v[i]; }
    #pragma unroll
    for (int m = 1; m < 64; m <<= 1) q += __shfl_xor(q, m);
    const float rstd = rsqrtf(q * (1.f / INNER) + LN_EPS);

    #pragma unroll
    for (int j = 0; j < 2; ++j) {
        const int c = j * 256 + lane * 4;
        float4 gv = *reinterpret_cast<const float4*>(g + c);
        float4 bv = *reinterpret_cast<const float4*>(be + c);
        float y0 = v[j*4+0] * rstd * gv.x + bv.x;
        float y1 = v[j*4+1] * rstd * gv.y + bv.y;
        float y2 = v[j*4+2] * rstd * gv.z + bv.z;
        float y3 = v[j*4+3] * rstd * gv.w + bv.w;
        if (out32) {
            float4 o = {y0, y1, y2, y3};
            *reinterpret_cast<float4*>(out32 + off + c) = o;
        }
        if (out16) {
            ushort4 o;
            o.x = f2bf(y0); o.y = f2bf(y1); o.z = f2bf(y2); o.w = f2bf(y3);
            *reinterpret_cast<ushort4*>(out16 + off + c) = o;
        }
    }
}

// ---------------------------------------------------------------- launch
extern "C" void kernel_launch(void* const* d_in, const int* in_sizes, int n_in,
                              void* d_out, int out_size, void* d_ws, size_t ws_size,
                              hipStream_t stream) {
    const float* x     = (const float*)d_in[0];
    const float* w_qkv = (const float*)d_in[1];
    const float* w_out = (const float*)d_in[2];
    const float* b_out = (const float*)d_in[3];
    const float* w_ff1 = (const float*)d_in[4];
    const float* w_ff2 = (const float*)d_in[5];
    const float* g1    = (const float*)d_in[6];
    const float* be1   = (const float*)d_in[7];
    const float* g2    = (const float*)d_in[8];
    const float* be2   = (const float*)d_in[9];
    float* out = (float*)d_out;

    char* W = (char*)d_ws;
    // Phases: A prep, B qkv, C attn, D combine, E proj, F LN1, G ff1, H ff2, I LN2
    u16*   w_outT     = (u16*)  (W + 0);          // 0.52 [A->E]
    u16*   w_ff1T     = (u16*)  (W + 524288);     // 2.10 [A->G]
    u16*   w_ff2T     = (u16*)  (W + 2621440);    // 2.10 [A->H]
    u16*   qk_b       = (u16*)  (W + 4718592);    // 8.39 (q then k) [B->C]
    float* proj       = (float*)(W + 4718592);    // 8.39 [E->F] (reuse qk_b)
    u16*   ff2p       = (u16*)  (W + 4718592);    // 8.39 (2 bf16 partials) [H->I]
    u16*   vT_b       = (u16*)  (W + 13107200);   // 4.19 [B->C]
    u16*   attn_res_b = (u16*)  (W + 13107200);   // 4.19 [F->I] (reuse vT_b)
    u16*   x_b        = (u16*)  (W + 17301504);   // 4.19 [A->B]
    u16*   w_qkvT     = (u16*)  (W + 21495808);   // 1.57 [A->B]
    u16*   OpartB     = (u16*)  (W + 17301504);   // 16.78 [C->D] (reuse x_b+w_qkvT)
    u16*   ff1_b      = (u16*)  (W + 17301504);   // 16.78 [G->H] (reuse OpartB)
    float* lpart      = (float*)(W + 34078720);   // 0.52 [C->D]
    u16*   attn_b     = (u16*)  (W + 34603008);   // 4.19 [D->E]  ends 38797312

    // A) fused prep: x->bf16 + 4 weight transposes (5120 blocks)
    prep_kernel<<<5120, 256, 0, stream>>>(x, x_b, w_qkv, w_qkvT, w_out, w_outT,
                                          w_ff1, w_ff1T, w_ff2, w_ff2T);

    // B) qkv = x @ w_qkv -> q(pre-scaled)/k rowmajor, V transposed (768 blocks)
    gemm_bt<64, 64, 2><<<dim3(1536 / 64, MROWS / 128), 256, 0, stream>>>(
        x_b, w_qkvT, nullptr, nullptr, qk_b, vT_b, MROWS, 1536, INNER);

    // C) attention partials (1024 blocks, 4/CU co-resident)
    attn_kernel<<<dim3(SEQ / 128, BATCH * HEADS, KSPLIT), 256, 0, stream>>>(
        qk_b, vT_b, OpartB, lpart);

    // D) combine -> bf16 (1024 blocks)
    attn_combine_kernel<<<(MROWS * INNER / 4) / 256, 256, 0, stream>>>(
        OpartB, lpart, attn_b);

    // E) proj = attn @ w_out + b_out -> fp32 (256 blocks)
    gemm_bt<64, 64, 1><<<dim3(INNER / 64, MROWS / 128), 256, 0, stream>>>(
        attn_b, w_outT, b_out, proj, nullptr, nullptr, MROWS, INNER, INNER);

    // F) attn_res = LN(x + proj) -> bf16
    ln_kernel<false, false, false><<<MROWS / 4, 256, 0, stream>>>(
        x, proj, nullptr, g1, be1, nullptr, attn_res_b);

    // G) ff1 = attn_res @ w_ff1 -> bf16 (512 blocks)
    gemm_bt<128, 64, 0><<<dim3(2048 / 128, MROWS / 128), 256, 0, stream>>>(
        attn_res_b, w_ff1T, nullptr, nullptr, ff1_b, nullptr, MROWS, 2048, INNER);

    // H) ff2 partials = ff1 @ w_ff2 (split-K=2) -> bf16 x2 (512 blocks)
    gemm_bt<64, 64, 3><<<dim3(INNER / 64, MROWS / 128, 2), 256, 0, stream>>>(
        ff1_b, w_ff2T, nullptr, nullptr, ff2p, nullptr, MROWS, INNER, 2048);

    // I) out = LN(attn_res + ff2p0 + ff2p1) -> fp32 d_out
    ln_kernel<true, true, true><<<MROWS / 4, 256, 0, stream>>>(
        attn_res_b, ff2p, ff2p + (size_t)MROWS * INNER, g2, be2, out, nullptr);
}

// Round 10
// 203.893 us; speedup vs baseline: 1.1434x; 1.0141x over previous
//
#include <hip/hip_runtime.h>
#include <hip/hip_bf16.h>
#include <cstdint>
#include <cstddef>
#include <math.h>

#define HEADS 8
#define DHEAD 64
#define INNER 512
#define BATCH 2
#define SEQ   2048
#define MROWS (BATCH*SEQ)   /* 4096 */
#define LN_EPS 1e-6f
#define KSPLIT 4
#define KCHUNK (SEQ/KSPLIT) /* 512 */
#define QSCALE 0.18033688011110918f   /* 0.125 * log2(e), folded into Q */

typedef unsigned short u16;
typedef __attribute__((ext_vector_type(8))) short short8;
typedef __attribute__((ext_vector_type(4))) short short4v;
typedef __attribute__((ext_vector_type(4))) float f32x4;

#define MFMA16(a,b,c) __builtin_amdgcn_mfma_f32_16x16x32_bf16((a),(b),(c),0,0,0)
#if __has_builtin(__builtin_amdgcn_mfma_f32_16x16x16bf16_1k)
#define HAVE_MFMA16K16 1
#define MFMA16K16(a,b,c) __builtin_amdgcn_mfma_f32_16x16x16bf16_1k((a),(b),(c),0,0,0)
#endif

__device__ __forceinline__ float bf2f(u16 u) {
    union { float f; uint32_t i; } x; x.i = ((uint32_t)u) << 16; return x.f;
}
__device__ __forceinline__ u16 f2bf(float f) {
    __hip_bfloat16 h = __float2bfloat16(f);   // RNE
    return *reinterpret_cast<u16*>(&h);
}
__device__ __forceinline__ void gl_lds16(const void* g, void* l) {
    __builtin_amdgcn_global_load_lds(
        (const __attribute__((address_space(1))) void*)g,
        (__attribute__((address_space(3))) void*)l, 16, 0, 0);
}

// ---------------------------------------------------------------- prep
__global__ void prep_kernel(const float* __restrict__ x, u16* __restrict__ x_b,
                            const float* __restrict__ w_qkv, u16* __restrict__ w_qkvT,
                            const float* __restrict__ w_out, u16* __restrict__ w_outT,
                            const float* __restrict__ w_ff1, u16* __restrict__ w_ff1T,
                            const float* __restrict__ w_ff2, u16* __restrict__ w_ff2T) {
    __shared__ float T[32][33];
    const int blk = blockIdx.x, tid = threadIdx.x;
    if (blk < 2048) {
        int i = blk * 256 + tid;
        float4 v = reinterpret_cast<const float4*>(x)[i];
        ushort4 o;
        o.x = f2bf(v.x); o.y = f2bf(v.y); o.z = f2bf(v.z); o.w = f2bf(v.w);
        reinterpret_cast<ushort4*>(x_b)[i] = o;
        return;
    }
    const float* B; u16* Bt; int K, N, t;
    if (blk < 2816)      { B = w_qkv; Bt = w_qkvT; K = 512;  N = 1536; t = blk - 2048; }
    else if (blk < 3072) { B = w_out; Bt = w_outT; K = 512;  N = 512;  t = blk - 2816; }
    else if (blk < 4096) { B = w_ff1; Bt = w_ff1T; K = 512;  N = 2048; t = blk - 3072; }
    else                 { B = w_ff2; Bt = w_ff2T; K = 2048; N = 512;  t = blk - 4096; }
    const int nb = N / 32;
    const int n0 = (t % nb) * 32, k0 = (t / nb) * 32;
    const int r = tid >> 3, c = (tid & 7) * 4;
    float4 v = *reinterpret_cast<const float4*>(&B[(size_t)(k0 + r) * N + n0 + c]);
    T[c + 0][r] = v.x; T[c + 1][r] = v.y; T[c + 2][r] = v.z; T[c + 3][r] = v.w;
    __syncthreads();
    ushort4 o;
    o.x = f2bf(T[r][c + 0]); o.y = f2bf(T[r][c + 1]);
    o.z = f2bf(T[r][c + 2]); o.w = f2bf(T[r][c + 3]);
    *reinterpret_cast<ushort4*>(&Bt[(size_t)(n0 + r) * K + k0 + c]) = o;
}

// ---------------------------------------------------------------- MFMA GEMM
// C[M,N] = A[M,K](bf16) @ Bt[N,K](bf16)^T. 128xBN tile, BK-deep k-steps,
// 4 waves. EPI: 0 bf16 out; 2 QKV routing; 3 bf16 split-K partial (z-index).
template<int BN, int BK, int EPI>
__global__ __launch_bounds__(256) void gemm_bt(const u16* __restrict__ A,
                                               const u16* __restrict__ Bt,
                                               u16* __restrict__ Cb,
                                               u16* __restrict__ Vt,
                                               int M, int N, int K) {
    constexpr int WN = BN / 2;
    constexpr int NT = WN / 16;
    constexpr int ACH = 128 * BK / 8;
    constexpr int BCH = BN * BK / 8;
    constexpr int CW = BK / 8;
    __shared__ u16 As[128 * BK];
    __shared__ u16 Bs[BN * BK];
    const int tid = threadIdx.x;
    const int wave = tid >> 6, lane = tid & 63;
    const int l15 = lane & 15, quad = lane >> 4;
    const int wm = (wave >> 1) * 64, wn = (wave & 1) * WN;
    const int row0 = blockIdx.y * 128, col0 = blockIdx.x * BN;

    int kbase = 0, kend = K;
    if (EPI == 3) {
        int chunk = K / gridDim.z;
        kbase = blockIdx.z * chunk; kend = kbase + chunk;
    }

    f32x4 acc[4][NT];
    #pragma unroll
    for (int mi = 0; mi < 4; ++mi)
        #pragma unroll
        for (int ni = 0; ni < NT; ++ni)
            #pragma unroll
            for (int e = 0; e < 4; ++e) acc[mi][ni][e] = 0.f;

    for (int k0 = kbase; k0 < kend; k0 += BK) {
        #pragma unroll
        for (int idx0 = 0; idx0 < ACH + BCH; idx0 += 256) {
            int idx = idx0 + tid;
            if (idx < ACH) {
                int r = idx / CW, ic = (idx % CW) * 8;
                gl_lds16(A + (size_t)(row0 + r) * K + k0 + ic, &As[idx * 8]);
            } else {
                int ib = idx - ACH;
                int r = ib / CW, ic = (ib % CW) * 8;
                gl_lds16(Bt + (size_t)(col0 + r) * K + k0 + ic, &Bs[ib * 8]);
            }
        }
        __syncthreads();

        #pragma unroll
        for (int ks2 = 0; ks2 < BK / 32; ++ks2) {
            short8 af[4], bfr[NT];
            #pragma unroll
            for (int mi = 0; mi < 4; ++mi)
                af[mi] = *reinterpret_cast<const short8*>(
                    &As[(wm + mi * 16 + l15) * BK + ks2 * 32 + quad * 8]);
            #pragma unroll
            for (int ni = 0; ni < NT; ++ni)
                bfr[ni] = *reinterpret_cast<const short8*>(
                    &Bs[(wn + ni * 16 + l15) * BK + ks2 * 32 + quad * 8]);
            #pragma unroll
            for (int mi = 0; mi < 4; ++mi)
                #pragma unroll
                for (int ni = 0; ni < NT; ++ni)
                    acc[mi][ni] = MFMA16(af[mi], bfr[ni], acc[mi][ni]);
        }
        __syncthreads();
    }

    #pragma unroll
    for (int mi = 0; mi < 4; ++mi)
        #pragma unroll
        for (int ni = 0; ni < NT; ++ni) {
            const int cc = col0 + wn + ni * 16 + l15;
            const int rr0 = row0 + wm + mi * 16 + quad * 4;
            if (EPI == 0) {
                #pragma unroll
                for (int r = 0; r < 4; ++r)
                    Cb[(size_t)(rr0 + r) * N + cc] = f2bf(acc[mi][ni][r]);
            } else if (EPI == 3) {
                u16* Cz = Cb + (size_t)blockIdx.z * M * N;
                #pragma unroll
                for (int r = 0; r < 4; ++r)
                    Cz[(size_t)(rr0 + r) * N + cc] = f2bf(acc[mi][ni][r]);
            } else {  // EPI == 2: QKV routing
                if (cc < 1024) {
                    const bool isq = (cc < 512);
                    size_t base = isq ? (size_t)cc
                                      : ((size_t)MROWS * 512 + cc - 512);
                    const float sc = isq ? QSCALE : 1.f;
                    #pragma unroll
                    for (int r = 0; r < 4; ++r)
                        Cb[base + (size_t)(rr0 + r) * 512] = f2bf(acc[mi][ni][r] * sc);
                } else {
                    int hh = (cc - 1024) >> 6, dd = (cc - 1024) & 63;
                    int bb = rr0 >> 11, srow = rr0 & 2047;
                    ushort4 o;
                    o.x = f2bf(acc[mi][ni][0]); o.y = f2bf(acc[mi][ni][1]);
                    o.z = f2bf(acc[mi][ni][2]); o.w = f2bf(acc[mi][ni][3]);
                    *reinterpret_cast<ushort4*>(
                        &Vt[(((size_t)(bb * 8 + hh) * 64 + dd) << 11) + srow]) = o;
                }
            }
        }
}

// ---------------------------------------------------------------- attention
// Block = (qtile 128 = 2x64, bh, ksplit 4). S^T = K*Q^T (Q pre-scaled);
// exp'd P feeds PV from registers (mfma 16x16x16, v_perm packs). l computed
// by an extra MFMA with A=ones (row-sum of P^T in the MFMA pipe, no VALU).
__global__ __launch_bounds__(256) void attn_kernel(const u16* __restrict__ qk_b,
                                                   const u16* __restrict__ vT_b,
                                                   u16* __restrict__ OpartB,
                                                   float* __restrict__ lpart) {
    __shared__ u16 SM[2 * 64 * 64 + 2 * 64 * 72];   // 34816 B
    u16 (*Qs)[64] = (u16(*)[64])SM;
    u16 (*Ks)[72] = (u16(*)[72])(SM + 2 * 64 * 64);
    u16 (*VT)[72] = (u16(*)[72])(SM + 2 * 64 * 64 + 64 * 72);

    const int tid = threadIdx.x;
    const int wave = tid >> 6, lane = tid & 63;
    const int l15 = lane & 15, quad = lane >> 4;
    const int qt = blockIdx.x, bh = blockIdx.y, ks = blockIdx.z;
    const int b = bh >> 3, h = bh & 7;
    const int w16 = wave * 16;
    const int r0 = tid >> 3, r1 = r0 + 32;
    const int ch = (tid & 7) * 8;

    {
        const u16* qb = qk_b + (size_t)(b * SEQ + qt * 128) * 512 + h * 64;
        #pragma unroll
        for (int j = 0; j < 4; ++j) {
            int idx = tid + j * 256;
            int r = idx >> 3, c = (idx & 7) * 8;
            *reinterpret_cast<uint4*>(&Qs[r][c]) =
                *reinterpret_cast<const uint4*>(&qb[(size_t)r * 512 + c]);
        }
    }
    __syncthreads();

    short8 qf[2][2];
    #pragma unroll
    for (int t = 0; t < 2; ++t) {
        qf[t][0] = *reinterpret_cast<const short8*>(&Qs[t * 64 + w16 + l15][quad * 8]);
        qf[t][1] = *reinterpret_cast<const short8*>(&Qs[t * 64 + w16 + l15][32 + quad * 8]);
    }

    const u16* kb = qk_b + (size_t)MROWS * 512
                  + (size_t)(b * SEQ + ks * KCHUNK) * 512 + h * 64;
    const u16* vb = vT_b + (size_t)bh * 64 * 2048 + ks * KCHUNK;

    uint4 kr0 = *reinterpret_cast<const uint4*>(&kb[(size_t)r0 * 512 + ch]);
    uint4 kr1 = *reinterpret_cast<const uint4*>(&kb[(size_t)r1 * 512 + ch]);
    uint4 vr0 = *reinterpret_cast<const uint4*>(&vb[(size_t)r0 * 2048 + ch]);
    uint4 vr1 = *reinterpret_cast<const uint4*>(&vb[(size_t)r1 * 2048 + ch]);

#ifdef HAVE_MFMA16K16
    const short ONEB = (short)0x3F80;               // bf16 1.0
    const short4v ones = {ONEB, ONEB, ONEB, ONEB};

    f32x4 oacc[2][4], lacc[2];
    #pragma unroll
    for (int t = 0; t < 2; ++t) {
        #pragma unroll
        for (int di = 0; di < 4; ++di)
            #pragma unroll
            for (int e = 0; e < 4; ++e) oacc[t][di][e] = 0.f;
        #pragma unroll
        for (int e = 0; e < 4; ++e) lacc[t][e] = 0.f;
    }

    for (int kt = 0; kt < KCHUNK / 64; ++kt) {
        *reinterpret_cast<uint4*>(&Ks[r0][ch]) = kr0;
        *reinterpret_cast<uint4*>(&Ks[r1][ch]) = kr1;
        *reinterpret_cast<uint4*>(&VT[r0][ch]) = vr0;
        *reinterpret_cast<uint4*>(&VT[r1][ch]) = vr1;
        __syncthreads();

        if (kt + 1 < KCHUNK / 64) {
            const u16* kb2 = kb + (size_t)(kt + 1) * 64 * 512;
            const u16* vb2 = vb + (kt + 1) * 64;
            kr0 = *reinterpret_cast<const uint4*>(&kb2[(size_t)r0 * 512 + ch]);
            kr1 = *reinterpret_cast<const uint4*>(&kb2[(size_t)r1 * 512 + ch]);
            vr0 = *reinterpret_cast<const uint4*>(&vb2[(size_t)r0 * 2048 + ch]);
            vr1 = *reinterpret_cast<const uint4*>(&vb2[(size_t)r1 * 2048 + ch]);
        }

        short8 kf[4], kf2[4];
        #pragma unroll
        for (int ni = 0; ni < 4; ++ni) {
            kf[ni]  = *reinterpret_cast<const short8*>(&Ks[ni * 16 + l15][quad * 8]);
            kf2[ni] = *reinterpret_cast<const short8*>(&Ks[ni * 16 + l15][32 + quad * 8]);
        }

        #pragma unroll
        for (int t = 0; t < 2; ++t) {
            f32x4 sacc[4];
            #pragma unroll
            for (int ni = 0; ni < 4; ++ni)
                #pragma unroll
                for (int e = 0; e < 4; ++e) sacc[ni][e] = 0.f;
            #pragma unroll
            for (int ni = 0; ni < 4; ++ni)
                sacc[ni] = MFMA16(kf[ni], qf[t][0], sacc[ni]);
            #pragma unroll
            for (int ni = 0; ni < 4; ++ni)
                sacc[ni] = MFMA16(kf2[ni], qf[t][1], sacc[ni]);

            #pragma unroll
            for (int ni = 0; ni < 4; ++ni) {
                float p0 = exp2f(sacc[ni][0]);
                float p1 = exp2f(sacc[ni][1]);
                float p2 = exp2f(sacc[ni][2]);
                float p3 = exp2f(sacc[ni][3]);
                union { short4v v; uint32_t u[2]; } P;
                P.u[0] = __builtin_amdgcn_perm(__float_as_uint(p1),
                                               __float_as_uint(p0), 0x07060302u);
                P.u[1] = __builtin_amdgcn_perm(__float_as_uint(p3),
                                               __float_as_uint(p2), 0x07060302u);
                lacc[t] = MFMA16K16(ones, P.v, lacc[t]);   // l += rowsum(P^T)
                #pragma unroll
                for (int di = 0; di < 4; ++di) {
                    short4v vf = *reinterpret_cast<const short4v*>(
                        &VT[di * 16 + l15][ni * 16 + quad * 4]);
                    oacc[t][di] = MFMA16K16(vf, P.v, oacc[t][di]);  // O^T += V^T P^T
                }
            }
        }
        __syncthreads();
    }

    // lacc rows are identical; col l15 = query w16+l15. Complete (MFMA sums k).
    const size_t pbase = ((size_t)(ks * 16 + bh) * SEQ + qt * 128);
    if (lane < 16) {
        lpart[pbase + w16 + lane]      = lacc[0][0];
        lpart[pbase + 64 + w16 + lane] = lacc[1][0];
    }

    // transpose O^T -> row-major bf16 partials via LDS
    float* OTf = (float*)SM;   // [64 d][68 q]
    const int ql = tid >> 2, dseg = (tid & 3) * 16;
    #pragma unroll
    for (int t = 0; t < 2; ++t) {
        __syncthreads();
        #pragma unroll
        for (int di = 0; di < 4; ++di)
            #pragma unroll
            for (int r = 0; r < 4; ++r)
                OTf[(di * 16 + quad * 4 + r) * 68 + w16 + l15] = oacc[t][di][r];
        __syncthreads();
        u16 ov[16];
        #pragma unroll
        for (int i = 0; i < 16; ++i) ov[i] = f2bf(OTf[(dseg + i) * 68 + ql]);
        u16* op = &OpartB[(pbase + t * 64 + ql) * 64 + dseg];
        *reinterpret_cast<uint4*>(op)     = *reinterpret_cast<const uint4*>(ov);
        *reinterpret_cast<uint4*>(op + 8) = *reinterpret_cast<const uint4*>(ov + 8);
    }
#else
    // fallback: per-tile P round-trip through Qs (wave-private rows)
    f32x4 oacc[2][4];
    float lsum[2][4];
    #pragma unroll
    for (int t = 0; t < 2; ++t)
        #pragma unroll
        for (int di = 0; di < 4; ++di) {
            #pragma unroll
            for (int e = 0; e < 4; ++e) oacc[t][di][e] = 0.f;
            lsum[t][di] = 0.f;
        }

    for (int kt = 0; kt < KCHUNK / 64; ++kt) {
        *reinterpret_cast<uint4*>(&Ks[r0][ch]) = kr0;
        *reinterpret_cast<uint4*>(&Ks[r1][ch]) = kr1;
        *reinterpret_cast<uint4*>(&VT[r0][ch]) = vr0;
        *reinterpret_cast<uint4*>(&VT[r1][ch]) = vr1;
        __syncthreads();

        if (kt + 1 < KCHUNK / 64) {
            const u16* kb2 = kb + (size_t)(kt + 1) * 64 * 512;
            const u16* vb2 = vb + (kt + 1) * 64;
            kr0 = *reinterpret_cast<const uint4*>(&kb2[(size_t)r0 * 512 + ch]);
            kr1 = *reinterpret_cast<const uint4*>(&kb2[(size_t)r1 * 512 + ch]);
            vr0 = *reinterpret_cast<const uint4*>(&vb2[(size_t)r0 * 2048 + ch]);
            vr1 = *reinterpret_cast<const uint4*>(&vb2[(size_t)r1 * 2048 + ch]);
        }

        #pragma unroll
        for (int t = 0; t < 2; ++t) {
            f32x4 sacc[4];
            #pragma unroll
            for (int ni = 0; ni < 4; ++ni)
                #pragma unroll
                for (int e = 0; e < 4; ++e) sacc[ni][e] = 0.f;
            #pragma unroll
            for (int ksk = 0; ksk < 2; ++ksk) {
                short8 kf[4];
                #pragma unroll
                for (int ni = 0; ni < 4; ++ni)
                    kf[ni] = *reinterpret_cast<const short8*>(
                        &Ks[ni * 16 + l15][ksk * 32 + quad * 8]);
                #pragma unroll
                for (int ni = 0; ni < 4; ++ni)
                    sacc[ni] = MFMA16(qf[t][ksk], kf[ni], sacc[ni]);
            }
            #pragma unroll
            for (int ni = 0; ni < 4; ++ni)
                #pragma unroll
                for (int r = 0; r < 4; ++r) {
                    float p = exp2f(sacc[ni][r]);
                    lsum[t][r] += p;
                    Qs[t * 64 + w16 + quad * 4 + r][ni * 16 + l15] = f2bf(p);
                }
            #pragma unroll
            for (int ksk = 0; ksk < 2; ++ksk) {
                short8 pf = *reinterpret_cast<const short8*>(
                    &Qs[t * 64 + w16 + l15][ksk * 32 + quad * 8]);
                #pragma unroll
                for (int di = 0; di < 4; ++di) {
                    short8 vf = *reinterpret_cast<const short8*>(
                        &VT[di * 16 + l15][ksk * 32 + quad * 8]);
                    oacc[t][di] = MFMA16(pf, vf, oacc[t][di]);
                }
            }
        }
        __syncthreads();
    }

    const size_t pbase = ((size_t)(ks * 16 + bh) * SEQ + qt * 128);
    #pragma unroll
    for (int t = 0; t < 2; ++t) {
        #pragma unroll
        for (int r = 0; r < 4; ++r) {
            float v = lsum[t][r];
            v += __shfl_xor(v, 1); v += __shfl_xor(v, 2);
            v += __shfl_xor(v, 4); v += __shfl_xor(v, 8);
            lsum[t][r] = v;
        }
        #pragma unroll
        for (int di = 0; di < 4; ++di)
            #pragma unroll
            for (int r = 0; r < 4; ++r)
                OpartB[(pbase + t * 64 + w16 + quad * 4 + r) * 64 + di * 16 + l15]
                    = f2bf(oacc[t][di][r]);
        if (l15 == 0)
            #pragma unroll
            for (int r = 0; r < 4; ++r)
                lpart[pbase + t * 64 + w16 + quad * 4 + r] = lsum[t][r];
    }
#endif
}

// combine: attn_b[row][h*64+d] = (sum_ks O) / (sum_ks l), 4 partials
__global__ void attn_combine_kernel(const u16* __restrict__ OpartB,
                                    const float* __restrict__ lpart,
                                    u16* __restrict__ attn_b) {
    int i = blockIdx.x * 256 + threadIdx.x;     // ushort4 index
    int e = i * 4;
    int row = e >> 9;
    int c = e & 511;
    int h = c >> 6, d = c & 63;
    int b = row >> 11, srow = row & 2047;
    int bh = b * 8 + h;

    float ax = 0.f, ay = 0.f, az = 0.f, aw = 0.f, l = 0.f;
    #pragma unroll
    for (int ks = 0; ks < KSPLIT; ++ks) {
        size_t pk = (size_t)(ks * 16 + bh) * SEQ + srow;
        ushort4 o = *reinterpret_cast<const ushort4*>(&OpartB[pk * 64 + d]);
        ax += bf2f(o.x); ay += bf2f(o.y); az += bf2f(o.z); aw += bf2f(o.w);
        l += lpart[pk];
    }
    float li = 1.f / l;
    ushort4 o;
    o.x = f2bf(ax * li); o.y = f2bf(ay * li);
    o.z = f2bf(az * li); o.w = f2bf(aw * li);
    *reinterpret_cast<ushort4*>(&attn_b[(size_t)row * INNER + c]) = o;
}

// ---------------------------------------------------------------- layernorm
// One wave per row. y = LN(a + sum_{i<NS} s_i + bias?) * g + be.
// a fp32 (A16=false) or bf16; s_i are bf16 partial planes stride sstride.
template<bool A16, int NS>
__global__ __launch_bounds__(256) void ln_kernel(const void* __restrict__ a_,
                                                 const u16* __restrict__ s_,
                                                 size_t sstride,
                                                 const float* __restrict__ bias,
                                                 const float* __restrict__ g,
                                                 const float* __restrict__ be,
                                                 float* __restrict__ out32,
                                                 u16* __restrict__ out16) {
    const int tid = threadIdx.x, wave = tid >> 6, lane = tid & 63;
    const int row = blockIdx.x * 4 + wave;
    const size_t off = (size_t)row * INNER;

    float v[8];
    #pragma unroll
    for (int j = 0; j < 2; ++j) {
        const int c = j * 256 + lane * 4;
        if (A16) {
            ushort4 u = *reinterpret_cast<const ushort4*>((const u16*)a_ + off + c);
            v[j*4+0] = bf2f(u.x); v[j*4+1] = bf2f(u.y);
            v[j*4+2] = bf2f(u.z); v[j*4+3] = bf2f(u.w);
        } else {
            float4 u = *reinterpret_cast<const float4*>((const float*)a_ + off + c);
            v[j*4+0] = u.x; v[j*4+1] = u.y; v[j*4+2] = u.z; v[j*4+3] = u.w;
        }
        #pragma unroll
        for (int s = 0; s < NS; ++s) {
            ushort4 u = *reinterpret_cast<const ushort4*>(
                s_ + (size_t)s * sstride + off + c);
            v[j*4+0] += bf2f(u.x); v[j*4+1] += bf2f(u.y);
            v[j*4+2] += bf2f(u.z); v[j*4+3] += bf2f(u.w);
        }
        if (bias) {
            float4 u = *reinterpret_cast<const float4*>(bias + c);
            v[j*4+0] += u.x; v[j*4+1] += u.y; v[j*4+2] += u.z; v[j*4+3] += u.w;
        }
    }

    float s = 0.f;
    #pragma unroll
    for (int i = 0; i < 8; ++i) s += v[i];
    #pragma unroll
    for (int m = 1; m < 64; m <<= 1) s += __shfl_xor(s, m);
    const float mu = s * (1.f / INNER);

    float q = 0.f;
    #pragma unroll
    for (int i = 0; i < 8; ++i) { v[i] -= mu; q += v[i] * v[i]; }
    #pragma unroll
    for (int m = 1; m < 64; m <<= 1) q += __shfl_xor(q, m);
    const float rstd = rsqrtf(q * (1.f / INNER) + LN_EPS);

    #pragma unroll
    for (int j = 0; j < 2; ++j) {
        const int c = j * 256 + lane * 4;
        float4 gv = *reinterpret_cast<const float4*>(g + c);
        float4 bv = *reinterpret_cast<const float4*>(be + c);
        float y0 = v[j*4+0] * rstd * gv.x + bv.x;
        float y1 = v[j*4+1] * rstd * gv.y + bv.y;
        float y2 = v[j*4+2] * rstd * gv.z + bv.z;
        float y3 = v[j*4+3] * rstd * gv.w + bv.w;
        if (out32) {
            float4 o = {y0, y1, y2, y3};
            *reinterpret_cast<float4*>(out32 + off + c) = o;
        }
        if (out16) {
            ushort4 o;
            o.x = f2bf(y0); o.y = f2bf(y1); o.z = f2bf(y2); o.w = f2bf(y3);
            *reinterpret_cast<ushort4*>(out16 + off + c) = o;
        }
    }
}

// ---------------------------------------------------------------- launch
extern "C" void kernel_launch(void* const* d_in, const int* in_sizes, int n_in,
                              void* d_out, int out_size, void* d_ws, size_t ws_size,
                              hipStream_t stream) {
    const float* x     = (const float*)d_in[0];
    const float* w_qkv = (const float*)d_in[1];
    const float* w_out = (const float*)d_in[2];
    const float* b_out = (const float*)d_in[3];
    const float* w_ff1 = (const float*)d_in[4];
    const float* w_ff2 = (const float*)d_in[5];
    const float* g1    = (const float*)d_in[6];
    const float* be1   = (const float*)d_in[7];
    const float* g2    = (const float*)d_in[8];
    const float* be2   = (const float*)d_in[9];
    float* out = (float*)d_out;

    char* W = (char*)d_ws;
    // Phases: A prep, B qkv, C attn, D combine, E proj, F LN1, G ff1, H ff2, I LN2
    u16*   w_outT     = (u16*)  (W + 0);          // 0.52 [A->E]
    u16*   w_ff1T     = (u16*)  (W + 524288);     // 2.10 [A->G]
    u16*   w_ff2T     = (u16*)  (W + 2621440);    // 2.10 [A->H]
    u16*   qk_b       = (u16*)  (W + 4718592);    // 8.39 (q then k) [B->C]
    u16*   projp      = (u16*)  (W + 4718592);    // 8.39 (2 bf16 partials) [E->F]
    u16*   vT_b       = (u16*)  (W + 13107200);   // 4.19 [B->C]
    u16*   attn_res_b = (u16*)  (W + 13107200);   // 4.19 [F->I] (reuse vT_b)
    u16*   x_b        = (u16*)  (W + 17301504);   // 4.19 [A->B]
    u16*   w_qkvT     = (u16*)  (W + 21495808);   // 1.57 [A->B]
    u16*   OpartB     = (u16*)  (W + 17301504);   // 16.78 [C->D] (reuse x_b+w_qkvT)
    u16*   ff1_b      = (u16*)  (W + 17301504);   // 16.78 [G->H] (reuse OpartB)
    float* lpart      = (float*)(W + 34078720);   // 0.52 [C->D]
    u16*   attn_b     = (u16*)  (W + 34603008);   // 4.19 [D->E]
    u16*   ff2p       = (u16*)  (W + 38797312);   // 16.78 (4 bf16 partials) [H->I]
                                                  // ends 55575552 (53 MiB)

    // A) fused prep: x->bf16 + 4 weight transposes (5120 blocks)
    prep_kernel<<<5120, 256, 0, stream>>>(x, x_b, w_qkv, w_qkvT, w_out, w_outT,
                                          w_ff1, w_ff1T, w_ff2, w_ff2T);

    // B) qkv = x @ w_qkv -> q(pre-scaled)/k rowmajor, V transposed (768 blocks)
    gemm_bt<64, 64, 2><<<dim3(1536 / 64, MROWS / 128), 256, 0, stream>>>(
        x_b, w_qkvT, qk_b, vT_b, MROWS, 1536, INNER);

    // C) attention partials (1024 blocks, 4/CU co-resident)
    attn_kernel<<<dim3(SEQ / 128, BATCH * HEADS, KSPLIT), 256, 0, stream>>>(
        qk_b, vT_b, OpartB, lpart);

    // D) combine -> bf16 (1024 blocks)
    attn_combine_kernel<<<(MROWS * INNER / 4) / 256, 256, 0, stream>>>(
        OpartB, lpart, attn_b);

    // E) proj partials = attn @ w_out (split-K=2) -> bf16 x2 (512 blocks)
    gemm_bt<64, 64, 3><<<dim3(INNER / 64, MROWS / 128, 2), 256, 0, stream>>>(
        attn_b, w_outT, projp, nullptr, MROWS, INNER, INNER);

    // F) attn_res = LN(x + projp0 + projp1 + b_out) -> bf16
    ln_kernel<false, 2><<<MROWS / 4, 256, 0, stream>>>(
        x, projp, (size_t)MROWS * INNER, b_out, g1, be1, nullptr, attn_res_b);

    // G) ff1 = attn_res @ w_ff1 -> bf16 (512 blocks)
    gemm_bt<128, 64, 0><<<dim3(2048 / 128, MROWS / 128), 256, 0, stream>>>(
        attn_res_b, w_ff1T, ff1_b, nullptr, MROWS, 2048, INNER);

    // H) ff2 partials = ff1 @ w_ff2 (split-K=4) -> bf16 x4 (1024 blocks)
    gemm_bt<64, 64, 3><<<dim3(INNER / 64, MROWS / 128, 4), 256, 0, stream>>>(
        ff1_b, w_ff2T, ff2p, nullptr, MROWS, INNER, 2048);

    // I) out = LN(attn_res + sum of 4 ff2 partials) -> fp32 d_out
    ln_kernel<true, 4><<<MROWS / 4, 256, 0, stream>>>(
        attn_res_b, ff2p, (size_t)MROWS * INNER, nullptr, g2, be2, out, nullptr);
}